// Round 1
// baseline (686.338 us; speedup 1.0000x reference)
//
#include <hip/hip_runtime.h>

typedef unsigned int uint;
typedef __fp16 half2_t __attribute__((ext_vector_type(2)));
typedef __fp16 half8_t __attribute__((ext_vector_type(8)));
typedef float floatx4 __attribute__((ext_vector_type(4)));

#define SEQ 512
#define BATCH 128
#define HID 128
#define NTAG 32
#define START_TAG 30
#define END_TAG 31

__device__ __forceinline__ float fdot2(uint a, uint b, float c) {
  return __builtin_amdgcn_fdot2(__builtin_bit_cast(half2_t, a),
                                __builtin_bit_cast(half2_t, b), c, false);
}
__device__ __forceinline__ uint packh2(float a, float b) {
  half2_t h = __builtin_amdgcn_cvt_pkrtz(a, b);
  return __builtin_bit_cast(uint, h);
}
__device__ __forceinline__ float frcp(float x) { return __builtin_amdgcn_rcpf(x); }
__device__ __forceinline__ float fsig(float x) { return frcp(1.f + __expf(-x)); }
__device__ __forceinline__ float ftanh(float x) { return 1.f - 2.f * frcp(1.f + __expf(2.f * x)); }
__device__ __forceinline__ float fexp2(float x) { return __builtin_amdgcn_exp2f(x); }
__device__ __forceinline__ float flog2(float x) { return __builtin_amdgcn_logf(x); }

// ---------------------------------------------------------------------------
// prep (unchanged from R8)
// ---------------------------------------------------------------------------
__global__ __launch_bounds__(256) void prep_kernel(
    const float* __restrict__ Wihf, const float* __restrict__ Whhf,
    const float* __restrict__ bihf, const float* __restrict__ bhhf,
    const float* __restrict__ Wihb, const float* __restrict__ Whhb,
    const float* __restrict__ bihb, const float* __restrict__ bhhb,
    const float* __restrict__ Wout,
    uint* __restrict__ wihI, uint* __restrict__ whh,
    uint* __restrict__ woutp, float* __restrict__ biasI)
{
  int idx = blockIdx.x * 256 + threadIdx.x;
  if (idx < 65536) {
    int d = idx >> 15, rem = idx & 32767;
    int n = rem >> 6, dw = rem & 63;
    int m = n >> 2, q = n & 3;
    int g = q * 128 + m;
    const float* W = d ? Wihb : Wihf;
    wihI[idx] = packh2(W[g * 128 + 2 * dw], W[g * 128 + 2 * dw + 1]);
  }
  int i2 = idx - 65536;
  if (i2 >= 0 && i2 < 65536) {
    int d = i2 >> 15, rem = i2 & 32767;
    int g = rem >> 6, dw = rem & 63;
    const float* W = d ? Whhb : Whhf;
    whh[i2] = packh2(W[g * 128 + 2 * dw], W[g * 128 + 2 * dw + 1]);
  }
  int i3 = idx - 131072;
  if (i3 >= 0 && i3 < 4096) {
    int k = i3 >> 7, dw = i3 & 127;
    float a, b2;
    if (dw < 64) { a = Wout[k * 256 + 2 * dw]; b2 = Wout[k * 256 + 2 * dw + 1]; }
    else { int j = dw - 64; a = Wout[k * 256 + 128 + 2 * j]; b2 = Wout[k * 256 + 128 + 2 * j + 1]; }
    woutp[i3] = packh2(a, b2);
  }
  int i4 = idx - 135168;
  if (i4 >= 0 && i4 < 1024) {
    int d = i4 >> 9, n = i4 & 511;
    int g = (n & 3) * 128 + (n >> 2);
    biasI[i4] = d ? (bihb[g] + bhhb[g]) : (bihf[g] + bhhf[g]);
  }
}

// ---------------------------------------------------------------------------
// gemmx (unchanged from R8)
// ---------------------------------------------------------------------------
__global__ __launch_bounds__(256, 2) void gemmx_kernel(
    const int* __restrict__ sentence, const float* __restrict__ embed,
    const uint* __restrict__ wihI, const float* __restrict__ biasI,
    uint* __restrict__ gatex, int chunk)
{
  int blk = blockIdx.x;
  int tl = blk & 127, nb = (blk >> 7) & 3, d = blk >> 9;
  int t = chunk * 128 + tl;
  int s = d ? (511 - t) : t;
  __shared__ int tok[128];
  int tid = threadIdx.x;
  if (tid < 128) tok[tid] = sentence[tid * SEQ + s];
  __syncthreads();

  int w = tid >> 6, lane = tid & 63;
  int q = lane >> 4, r = lane & 15;
  int wr = w >> 1, wc = w & 1;
  int r0 = wr * 64;
  int c0 = nb * 128 + wc * 64;

  floatx4 acc[4][4];
#pragma unroll
  for (int i = 0; i < 4; ++i)
#pragma unroll
    for (int j = 0; j < 4; ++j) acc[i][j] = (floatx4){0.f, 0.f, 0.f, 0.f};

  const float4* aptr[4];
#pragma unroll
  for (int i = 0; i < 4; ++i)
    aptr[i] = (const float4*)(embed + (size_t)tok[r0 + i * 16 + r] * HID) + q * 2;
  const uint4* bptr[4];
#pragma unroll
  for (int j = 0; j < 4; ++j)
    bptr[j] = (const uint4*)(wihI + ((size_t)d * 512 + c0 + j * 16 + r) * 64) + q;

#pragma unroll
  for (int kc = 0; kc < 4; ++kc) {
    half8_t af[4], bf[4];
#pragma unroll
    for (int i = 0; i < 4; ++i) {
      float4 x0 = aptr[i][kc * 8];
      float4 x1 = aptr[i][kc * 8 + 1];
      uint4 u;
      u.x = packh2(x0.x, x0.y); u.y = packh2(x0.z, x0.w);
      u.z = packh2(x1.x, x1.y); u.w = packh2(x1.z, x1.w);
      af[i] = __builtin_bit_cast(half8_t, u);
    }
#pragma unroll
    for (int j = 0; j < 4; ++j)
      bf[j] = __builtin_bit_cast(half8_t, bptr[j][kc * 4]);
#pragma unroll
    for (int i = 0; i < 4; ++i)
#pragma unroll
      for (int j = 0; j < 4; ++j)
        acc[i][j] = __builtin_amdgcn_mfma_f32_16x16x32_f16(af[i], bf[j], acc[i][j], 0, 0, 0);
  }

  __fp16* gat = ((__fp16*)gatex) + (size_t)d * 16384 * 512;
#pragma unroll
  for (int j = 0; j < 4; ++j) {
    int n = c0 + j * 16 + r;
    float bb = biasI[d * 512 + n];
#pragma unroll
    for (int i = 0; i < 4; ++i) {
      int rb = r0 + i * 16 + q * 4;
#pragma unroll
      for (int reg = 0; reg < 4; ++reg) {
        float v = acc[i][j][reg] + bb;
        gat[((size_t)(tl * 128 + rb + reg)) * 512 + n] = (__fp16)v;
      }
    }
  }
}

// ---------------------------------------------------------------------------
// LSTM recurrence. One WG per (d,b); grid = 256 = 1 block/CU.
// R10 change: R9's LDS-pad trick FAILED (pad was dead-code-eliminated:
// LDS_Block_Size stayed 32768, VGPR_Count stayed 84 < the 128 VGPRs wreg
// needs) -> the compiler sank the weight loads into the 128-step loop,
// re-streaming up to 128KB/WG of whh from L2 EVERY step with 1 wave/SIMD
// and nothing to hide it (the ~1200 stall cycles/step seen in rocprof).
// Fix: asm volatile "+v" anchors on every wreg component after preload.
// The values become opaque asm results -> not rematerializable -> the
// allocator must keep all 128 weight VGPRs live across the recurrence.
// ---------------------------------------------------------------------------
__global__ __launch_bounds__(256, 1) void lstm_kernel(
    const uint* __restrict__ gatex, const uint* __restrict__ whh,
    const float* __restrict__ h0, const float* __restrict__ c0,
    float* __restrict__ statec, uint* __restrict__ hh, int chunk)
{
  const int wg = blockIdx.x;
  const int d = wg >> 7, b = wg & 127;
  const int tid = threadIdx.x;
  const int w = tid >> 6, lane = tid & 63;
  const int hp = lane >> 5, r = lane & 31;
  const int m = w * 32 + r;

  __shared__ __align__(16) __fp16 hist[128][128];   // 32 KB

  const uint4* wh4 = (const uint4*)(whh + (size_t)d * 512 * 64);
  uint4 wreg[4][8];
#pragma unroll
  for (int q = 0; q < 4; ++q) {
    const uint4* row = wh4 + (q * 128 + m) * 16 + hp * 8;
#pragma unroll
    for (int i = 0; i < 8; ++i) wreg[q][i] = row[i];
  }
  // Anchor: force every weight dword into a live VGPR for the whole loop.
#pragma unroll
  for (int q = 0; q < 4; ++q)
#pragma unroll
    for (int i = 0; i < 8; ++i)
      asm volatile("" : "+v"(wreg[q][i].x), "+v"(wreg[q][i].y),
                       "+v"(wreg[q][i].z), "+v"(wreg[q][i].w));

  float c = (chunk == 0) ? c0[(size_t)(d * 128 + b) * 128 + m]
                         : statec[(size_t)(d * 128 + b) * 128 + m];

  if (tid < 64) {
    uint* h127 = (uint*)&hist[127][0];
    if (chunk == 0) {
      float2 hv = ((const float2*)(h0 + (size_t)(d * 128 + b) * 128))[tid];
      h127[tid] = packh2(hv.x, hv.y);
    } else {
      int sprev = d ? (511 - (chunk * 128 - 1)) : (chunk * 128 - 1);
      h127[tid] = hh[((size_t)(d * 512 + sprev) * 128 + b) * 64 + tid];
    }
  }
  const uint* gx0 = gatex + (size_t)d * 4194304 + (size_t)b * 256 + 2 * m;
  uint2 gx = *(const uint2*)(gx0);
  __syncthreads();

  for (int tl = 0; tl < 128; ++tl) {
    uint2 gxn = gx;
    if (tl < 127) gxn = *(const uint2*)(gx0 + (size_t)(tl + 1) * 32768);

    float a0 = 0.f, a1 = 0.f, a2 = 0.f, a3 = 0.f;
    const uint4* z4 = (const uint4*)(&hist[(tl + 127) & 127][hp * 64]);
#pragma unroll
    for (int i = 0; i < 8; ++i) {
      uint4 z = z4[i];
      a0 = fdot2(z.x, wreg[0][i].x, a0);
      a0 = fdot2(z.y, wreg[0][i].y, a0);
      a0 = fdot2(z.z, wreg[0][i].z, a0);
      a0 = fdot2(z.w, wreg[0][i].w, a0);
      a1 = fdot2(z.x, wreg[1][i].x, a1);
      a1 = fdot2(z.y, wreg[1][i].y, a1);
      a1 = fdot2(z.z, wreg[1][i].z, a1);
      a1 = fdot2(z.w, wreg[1][i].w, a1);
      a2 = fdot2(z.x, wreg[2][i].x, a2);
      a2 = fdot2(z.y, wreg[2][i].y, a2);
      a2 = fdot2(z.z, wreg[2][i].z, a2);
      a2 = fdot2(z.w, wreg[2][i].w, a2);
      a3 = fdot2(z.x, wreg[3][i].x, a3);
      a3 = fdot2(z.y, wreg[3][i].y, a3);
      a3 = fdot2(z.z, wreg[3][i].z, a3);
      a3 = fdot2(z.w, wreg[3][i].w, a3);
    }
    a0 += __shfl_xor(a0, 32);
    a1 += __shfl_xor(a1, 32);
    a2 += __shfl_xor(a2, 32);
    a3 += __shfl_xor(a3, 32);

    half2_t g01 = __builtin_bit_cast(half2_t, gx.x);
    half2_t g23 = __builtin_bit_cast(half2_t, gx.y);
    a0 += (float)g01[0];
    a1 += (float)g01[1];
    a2 += (float)g23[0];
    a3 += (float)g23[1];

    float ig = fsig(a0);
    float fg = fsig(a1);
    float gg = ftanh(a2);
    float og = fsig(a3);
    c = fg * c + ig * gg;
    float hv = og * ftanh(c);

    if (hp == 0) hist[tl][m] = (__fp16)hv;
    gx = gxn;
    __syncthreads();
  }

  statec[(size_t)(d * 128 + b) * 128 + m] = c;

  int base = chunk * 128;
  for (int i = tid; i < 2048; i += 256) {
    int sl = i >> 4, q4 = i & 15;
    int s = d ? (511 - (base + sl)) : (base + sl);
    *(uint4*)(&hh[((size_t)(d * 512 + s) * 128 + b) * 64 + q4 * 4]) =
        *(const uint4*)((const uint*)&hist[sl][0] + q4 * 4);
  }
}

// ---------------------------------------------------------------------------
// Output projection (unchanged from R8)
// ---------------------------------------------------------------------------
__global__ __launch_bounds__(256) void outproj_kernel(
    const uint* __restrict__ hh, const uint* __restrict__ woutp,
    const float* __restrict__ bout, float* __restrict__ feats)
{
  __shared__ __align__(16) uint4 zrow[8][32];
  __shared__ __align__(16) uint4 wlds[32][32];
  int tid = threadIdx.x;
  for (int j = tid; j < 1024; j += 256) {
    int k = j >> 5, i = j & 31;
    wlds[i][k] = ((const uint4*)woutp)[j];
  }
  int rl = tid >> 5, q = tid & 31;
  int row = blockIdx.x * 8 + rl;
  int b = row >> 9, s = row & 511;
  const uint4* hf4 = (const uint4*)(hh + ((size_t)s * BATCH + b) * 64);
  const uint4* hb4 = (const uint4*)(hh + ((size_t)(SEQ + s) * BATCH + b) * 64);
  zrow[rl][q] = (q < 16) ? hf4[q] : hb4[q - 16];
  __syncthreads();
  int k = q;
  float acc = bout[k];
#pragma unroll
  for (int i = 0; i < 32; ++i) {
    uint4 z = zrow[rl][i];
    uint4 wv = wlds[i][k];
    acc = fdot2(z.x, wv.x, acc);
    acc = fdot2(z.y, wv.y, acc);
    acc = fdot2(z.z, wv.z, acc);
    acc = fdot2(z.w, wv.w, acc);
  }
  feats[(size_t)row * 32 + k] = acc;
}

// ---------------------------------------------------------------------------
// CRF numerator (unchanged)
// ---------------------------------------------------------------------------
__global__ __launch_bounds__(64) void crf_num_kernel(
    const int* __restrict__ tags, const float* __restrict__ feats,
    const float* __restrict__ trans, float* __restrict__ num)
{
  int b = blockIdx.x, l = threadIdx.x;
  const int* tb = tags + b * SEQ;
  float acc = 0.f;
  for (int s = l; s < SEQ; s += 64) {
    int tg = tb[s];
    int pv = (s == 0) ? START_TAG : tb[s - 1];
    acc += trans[pv * NTAG + tg] + feats[((size_t)b * SEQ + s) * NTAG + tg];
  }
#pragma unroll
  for (int msk = 1; msk < 64; msk <<= 1) acc += __shfl_xor(acc, msk);
  if (l == 0) num[b] = acc + trans[tb[SEQ - 1] * NTAG + END_TAG];
}

// ---------------------------------------------------------------------------
// CRF stage A (unchanged from R8)
// ---------------------------------------------------------------------------
__global__ __launch_bounds__(64) void crf_seg_kernel(
    const float* __restrict__ feats, const float* __restrict__ trans,
    uint* __restrict__ segP, float* __restrict__ segL)
{
  const float L2E = 1.4426950408889634f;
  int blk = blockIdx.x;
  int b = blk >> 5, j = blk & 31;
  int tstart = 1 + 16 * j;
  int nsteps = (j == 31) ? 15 : 16;
  int lane = threadIdx.x;
  int c = lane & 15, q = lane >> 4;

  half8_t afr[2];
#pragma unroll
  for (int rt = 0; rt < 2; ++rt) {
    const float* trow = trans + (rt * 16 + c) * 32 + q * 8;
    float e[8];
#pragma unroll
    for (int i = 0; i < 8; ++i) e[i] = fexp2(trow[i] * L2E);
    uint4 u;
    u.x = packh2(e[0], e[1]); u.y = packh2(e[2], e[3]);
    u.z = packh2(e[4], e[5]); u.w = packh2(e[6], e[7]);
    afr[rt] = __builtin_bit_cast(half8_t, u);
  }
  half8_t bfr[2];
#pragma unroll
  for (int ct = 0; ct < 2; ++ct) {
    uint4 u;
    uint vals[8];
#pragma unroll
    for (int i = 0; i < 8; ++i)
      vals[i] = ((q * 8 + i) == (ct * 16 + c)) ? 0x3C00u : 0u;
    u.x = vals[0] | (vals[1] << 16);
    u.y = vals[2] | (vals[3] << 16);
    u.z = vals[4] | (vals[5] << 16);
    u.w = vals[6] | (vals[7] << 16);
    bfr[ct] = __builtin_bit_cast(half8_t, u);
  }

  __shared__ __fp16 P16[32 * 36];

  const float* fb = feats + ((size_t)b * SEQ + tstart) * NTAG;
  float Lacc = 0.f;
  float4 pre0 = *(const float4*)(fb + q * 4);
  float4 pre1 = *(const float4*)(fb + 16 + q * 4);

  for (int s = 0; s < nsteps; ++s) {
    float4 f0 = pre0, f1 = pre1;
    if (s + 1 < nsteps) {
      pre0 = *(const float4*)(fb + (s + 1) * 32 + q * 4);
      pre1 = *(const float4*)(fb + (s + 1) * 32 + 16 + q * 4);
    }
    floatx4 z4 = (floatx4){0.f, 0.f, 0.f, 0.f};
    floatx4 c00 = __builtin_amdgcn_mfma_f32_16x16x32_f16(afr[0], bfr[0], z4, 0, 0, 0);
    floatx4 c01 = __builtin_amdgcn_mfma_f32_16x16x32_f16(afr[0], bfr[1], z4, 0, 0, 0);
    floatx4 c10 = __builtin_amdgcn_mfma_f32_16x16x32_f16(afr[1], bfr[0], z4, 0, 0, 0);
    floatx4 c11 = __builtin_amdgcn_mfma_f32_16x16x32_f16(afr[1], bfr[1], z4, 0, 0, 0);
    float pf0[4], pf1[4];
    pf0[0] = fexp2(f0.x * L2E); pf0[1] = fexp2(f0.y * L2E);
    pf0[2] = fexp2(f0.z * L2E); pf0[3] = fexp2(f0.w * L2E);
    pf1[0] = fexp2(f1.x * L2E); pf1[1] = fexp2(f1.y * L2E);
    pf1[2] = fexp2(f1.z * L2E); pf1[3] = fexp2(f1.w * L2E);
    float v00[4], v01[4], v10[4], v11[4];
#pragma unroll
    for (int rg = 0; rg < 4; ++rg) {
      v00[rg] = c00[rg] * pf0[rg];
      v01[rg] = c01[rg] * pf0[rg];
      v10[rg] = c10[rg] * pf1[rg];
      v11[rg] = c11[rg] * pf1[rg];
    }
    float mx = 0.f;
#pragma unroll
    for (int rg = 0; rg < 4; ++rg)
      mx = fmaxf(mx, fmaxf(fmaxf(v00[rg], v01[rg]), fmaxf(v10[rg], v11[rg])));
    uint ub = (uint)__builtin_amdgcn_readfirstlane((int)__builtin_bit_cast(uint, mx));
    int e = (int)((ub >> 23) & 255u);
    Lacc += (float)(e - 127);
    float sc = __builtin_bit_cast(float, (uint)((254 - e) << 23));

    __syncthreads();
    {
      uint2 wv2;
      wv2.x = packh2(v00[0] * sc, v00[1] * sc);
      wv2.y = packh2(v00[2] * sc, v00[3] * sc);
      *(uint2*)(&P16[c * 36 + q * 4]) = wv2;
      wv2.x = packh2(v10[0] * sc, v10[1] * sc);
      wv2.y = packh2(v10[2] * sc, v10[3] * sc);
      *(uint2*)(&P16[c * 36 + 16 + q * 4]) = wv2;
      wv2.x = packh2(v01[0] * sc, v01[1] * sc);
      wv2.y = packh2(v01[2] * sc, v01[3] * sc);
      *(uint2*)(&P16[(16 + c) * 36 + q * 4]) = wv2;
      wv2.x = packh2(v11[0] * sc, v11[1] * sc);
      wv2.y = packh2(v11[2] * sc, v11[3] * sc);
      *(uint2*)(&P16[(16 + c) * 36 + 16 + q * 4]) = wv2;
    }
    __syncthreads();
    {
      uint2 lo0 = *(const uint2*)(&P16[c * 36 + q * 8]);
      uint2 hi0 = *(const uint2*)(&P16[c * 36 + q * 8 + 4]);
      uint4 u0; u0.x = lo0.x; u0.y = lo0.y; u0.z = hi0.x; u0.w = hi0.y;
      bfr[0] = __builtin_bit_cast(half8_t, u0);
      uint2 lo1 = *(const uint2*)(&P16[(16 + c) * 36 + q * 8]);
      uint2 hi1 = *(const uint2*)(&P16[(16 + c) * 36 + q * 8 + 4]);
      uint4 u1; u1.x = lo1.x; u1.y = lo1.y; u1.z = hi1.x; u1.w = hi1.y;
      bfr[1] = __builtin_bit_cast(half8_t, u1);
    }
  }
  __syncthreads();
  uint* gp = segP + (size_t)blk * 512;
  if (lane < 32) {
    int i = lane;
#pragma unroll
    for (int tp = 0; tp < 16; ++tp) {
      uint lo = (uint)__builtin_bit_cast(unsigned short, P16[(2 * tp) * 36 + i]);
      uint hi = (uint)__builtin_bit_cast(unsigned short, P16[(2 * tp + 1) * 36 + i]);
      gp[i * 16 + tp] = lo | (hi << 16);
    }
  }
  if (lane == 0) segL[blk] = Lacc;
}

// ---------------------------------------------------------------------------
// CRF stage B (unchanged from R8)
// ---------------------------------------------------------------------------
__global__ __launch_bounds__(64) void crf_comb_kernel(
    const float* __restrict__ feats, const float* __restrict__ trans,
    const uint* __restrict__ segP, const float* __restrict__ segL,
    float* __restrict__ den)
{
  const float L2E = 1.4426950408889634f, LN2 = 0.6931471805599453f;
  int b = blockIdx.x, l = threadIdx.x;
  int i = l & 31, hp = l >> 5;
  const float* fb = feats + (size_t)b * SEQ * NTAG;

  float sT = 0.f;
  for (int p = 0; p < 32; ++p) sT += fexp2(trans[i * 32 + p] * L2E);
  float v = (1.f + sT) * fexp2(fb[i] * L2E);
  float L = -10000.f * L2E;

  float vo = __shfl_xor(v, 1);
  uint pv = (i & 1) ? packh2(vo, v) : packh2(v, vo);

  const uint* gp0 = segP + (size_t)b * 32 * 512 + i * 16 + hp * 8;
  uint4 ra = *(const uint4*)(gp0);
  uint4 rb = *(const uint4*)(gp0 + 4);

  for (int seg = 0; seg < 32; ++seg) {
    uint4 ca = ra, cb = rb;
    if (seg + 1 < 32) {
      ra = *(const uint4*)(gp0 + (seg + 1) * 512);
      rb = *(const uint4*)(gp0 + (seg + 1) * 512 + 4);
    }
    float g0 = __shfl(__builtin_bit_cast(float, pv), hp * 16 + 0);
    float g1 = __shfl(__builtin_bit_cast(float, pv), hp * 16 + 2);
    float g2 = __shfl(__builtin_bit_cast(float, pv), hp * 16 + 4);
    float g3 = __shfl(__builtin_bit_cast(float, pv), hp * 16 + 6);
    float g4 = __shfl(__builtin_bit_cast(float, pv), hp * 16 + 8);
    float g5 = __shfl(__builtin_bit_cast(float, pv), hp * 16 + 10);
    float g6 = __shfl(__builtin_bit_cast(float, pv), hp * 16 + 12);
    float g7 = __shfl(__builtin_bit_cast(float, pv), hp * 16 + 14);
    float acc = 0.f;
    acc = fdot2(__builtin_bit_cast(uint, g0), ca.x, acc);
    acc = fdot2(__builtin_bit_cast(uint, g1), ca.y, acc);
    acc = fdot2(__builtin_bit_cast(uint, g2), ca.z, acc);
    acc = fdot2(__builtin_bit_cast(uint, g3), ca.w, acc);
    acc = fdot2(__builtin_bit_cast(uint, g4), cb.x, acc);
    acc = fdot2(__builtin_bit_cast(uint, g5), cb.y, acc);
    acc = fdot2(__builtin_bit_cast(uint, g6), cb.z, acc);
    acc = fdot2(__builtin_bit_cast(uint, g7), cb.w, acc);
    float sm = acc + __shfl_xor(acc, 32);
    uint ub = (uint)__builtin_amdgcn_readfirstlane((int)__builtin_bit_cast(uint, sm));
    int e = (int)((ub >> 23) & 255u);
    L += (float)(e - 127) + segL[b * 32 + seg];
    float sc = __builtin_bit_cast(float, (uint)((254 - e) << 23));
    v = sm * sc;
    float vo2 = __shfl_xor(v, 1);
    pv = (i & 1) ? packh2(vo2, v) : packh2(v, vo2);
  }
  float wv = v * fexp2(trans[i * 32 + END_TAG] * L2E);
#pragma unroll
  for (int msk = 1; msk <= 16; msk <<= 1) wv += __shfl_xor(wv, msk);
  if (l == 0) den[b] = (L + flog2(wv)) * LN2;
}

__global__ __launch_bounds__(128) void final_kernel(
    const float* __restrict__ num, const float* __restrict__ den,
    float* __restrict__ out)
{
  int tid = threadIdx.x;
  float v = num[tid] - den[tid];
#pragma unroll
  for (int msk = 1; msk < 64; msk <<= 1) v += __shfl_xor(v, msk);
  __shared__ float tmp[2];
  if ((tid & 63) == 0) tmp[tid >> 6] = v;
  __syncthreads();
  if (tid == 0) out[0] = (tmp[0] + tmp[1]) * (1.f / 128.f);
}

// ---------------------------------------------------------------------------
// Workspace layout (bytes): same as R8 (~51.4 MB)
// ---------------------------------------------------------------------------
extern "C" void kernel_launch(void* const* d_in, const int* in_sizes, int n_in,
                              void* d_out, int out_size, void* d_ws, size_t ws_size,
                              hipStream_t stream)
{
  const int* sentence = (const int*)d_in[0];
  const int* tags = (const int*)d_in[1];
  const float* embed = (const float*)d_in[2];
  const float* Wihf = (const float*)d_in[3];
  const float* Whhf = (const float*)d_in[4];
  const float* bihf = (const float*)d_in[5];
  const float* bhhf = (const float*)d_in[6];
  const float* Wihb = (const float*)d_in[7];
  const float* Whhb = (const float*)d_in[8];
  const float* bihb = (const float*)d_in[9];
  const float* bhhb = (const float*)d_in[10];
  const float* Wout = (const float*)d_in[11];
  const float* bout = (const float*)d_in[12];
  const float* trans = (const float*)d_in[13];
  const float* h0 = (const float*)d_in[14];
  const float* c0 = (const float*)d_in[15];
  float* out = (float*)d_out;

  char* ws = (char*)d_ws;
  uint* wihI = (uint*)(ws + 0);
  uint* whh = (uint*)(ws + 262144);
  uint* woutp = (uint*)(ws + 524288);
  float* biasI = (float*)(ws + 540672);
  float* numb = (float*)(ws + 544768);
  float* denb = (float*)(ws + 545280);
  float* statec = (float*)(ws + 545792);
  uint* hh = (uint*)(ws + 1048576);
  uint* gatex = (uint*)(ws + 34603008);
  float* feats = (float*)(ws + 34603008);
  uint* segP = (uint*)(ws + 42991616);
  float* segL = (float*)(ws + 51380224);

  hipLaunchKernelGGL(prep_kernel, dim3(532), dim3(256), 0, stream,
                     Wihf, Whhf, bihf, bhhf, Wihb, Whhb, bihb, bhhb, Wout,
                     wihI, whh, woutp, biasI);
  for (int c = 0; c < 4; ++c) {
    hipLaunchKernelGGL(gemmx_kernel, dim3(1024), dim3(256), 0, stream,
                       sentence, embed, wihI, biasI, gatex, c);
    hipLaunchKernelGGL(lstm_kernel, dim3(256), dim3(256), 0, stream,
                       gatex, whh, h0, c0, statec, hh, c);
  }
  hipLaunchKernelGGL(outproj_kernel, dim3(8192), dim3(256), 0, stream,
                     hh, woutp, bout, feats);
  hipLaunchKernelGGL(crf_num_kernel, dim3(128), dim3(64), 0, stream,
                     tags, feats, trans, numb);
  hipLaunchKernelGGL(crf_seg_kernel, dim3(4096), dim3(64), 0, stream,
                     feats, trans, segP, segL);
  hipLaunchKernelGGL(crf_comb_kernel, dim3(128), dim3(64), 0, stream,
                     feats, trans, segP, segL, denb);
  hipLaunchKernelGGL(final_kernel, dim3(1), dim3(128), 0, stream,
                     numb, denb, out);
}

// Round 2
// 627.195 us; speedup vs baseline: 1.0943x; 1.0943x over previous
//
#include <hip/hip_runtime.h>

typedef unsigned int uint;
typedef __fp16 half2_t __attribute__((ext_vector_type(2)));
typedef __fp16 half8_t __attribute__((ext_vector_type(8)));
typedef float floatx4 __attribute__((ext_vector_type(4)));

#define SEQ 512
#define BATCH 128
#define HID 128
#define NTAG 32
#define START_TAG 30
#define END_TAG 31

__device__ __forceinline__ float fdot2(uint a, uint b, float c) {
  return __builtin_amdgcn_fdot2(__builtin_bit_cast(half2_t, a),
                                __builtin_bit_cast(half2_t, b), c, false);
}
__device__ __forceinline__ uint packh2(float a, float b) {
  half2_t h = __builtin_amdgcn_cvt_pkrtz(a, b);
  return __builtin_bit_cast(uint, h);
}
__device__ __forceinline__ float frcp(float x) { return __builtin_amdgcn_rcpf(x); }
__device__ __forceinline__ float fsig(float x) { return frcp(1.f + __expf(-x)); }
__device__ __forceinline__ float ftanh(float x) { return 1.f - 2.f * frcp(1.f + __expf(2.f * x)); }
__device__ __forceinline__ float fexp2(float x) { return __builtin_amdgcn_exp2f(x); }
__device__ __forceinline__ float flog2(float x) { return __builtin_amdgcn_logf(x); }

// ---------------------------------------------------------------------------
// prep (unchanged from R8)
// ---------------------------------------------------------------------------
__global__ __launch_bounds__(256) void prep_kernel(
    const float* __restrict__ Wihf, const float* __restrict__ Whhf,
    const float* __restrict__ bihf, const float* __restrict__ bhhf,
    const float* __restrict__ Wihb, const float* __restrict__ Whhb,
    const float* __restrict__ bihb, const float* __restrict__ bhhb,
    const float* __restrict__ Wout,
    uint* __restrict__ wihI, uint* __restrict__ whh,
    uint* __restrict__ woutp, float* __restrict__ biasI)
{
  int idx = blockIdx.x * 256 + threadIdx.x;
  if (idx < 65536) {
    int d = idx >> 15, rem = idx & 32767;
    int n = rem >> 6, dw = rem & 63;
    int m = n >> 2, q = n & 3;
    int g = q * 128 + m;
    const float* W = d ? Wihb : Wihf;
    wihI[idx] = packh2(W[g * 128 + 2 * dw], W[g * 128 + 2 * dw + 1]);
  }
  int i2 = idx - 65536;
  if (i2 >= 0 && i2 < 65536) {
    int d = i2 >> 15, rem = i2 & 32767;
    int g = rem >> 6, dw = rem & 63;
    const float* W = d ? Whhb : Whhf;
    whh[i2] = packh2(W[g * 128 + 2 * dw], W[g * 128 + 2 * dw + 1]);
  }
  int i3 = idx - 131072;
  if (i3 >= 0 && i3 < 4096) {
    int k = i3 >> 7, dw = i3 & 127;
    float a, b2;
    if (dw < 64) { a = Wout[k * 256 + 2 * dw]; b2 = Wout[k * 256 + 2 * dw + 1]; }
    else { int j = dw - 64; a = Wout[k * 256 + 128 + 2 * j]; b2 = Wout[k * 256 + 128 + 2 * j + 1]; }
    woutp[i3] = packh2(a, b2);
  }
  int i4 = idx - 135168;
  if (i4 >= 0 && i4 < 1024) {
    int d = i4 >> 9, n = i4 & 511;
    int g = (n & 3) * 128 + (n >> 2);
    biasI[i4] = d ? (bihb[g] + bhhb[g]) : (bihf[g] + bhhf[g]);
  }
}

// ---------------------------------------------------------------------------
// gemmx (unchanged from R8)
// ---------------------------------------------------------------------------
__global__ __launch_bounds__(256, 2) void gemmx_kernel(
    const int* __restrict__ sentence, const float* __restrict__ embed,
    const uint* __restrict__ wihI, const float* __restrict__ biasI,
    uint* __restrict__ gatex, int chunk)
{
  int blk = blockIdx.x;
  int tl = blk & 127, nb = (blk >> 7) & 3, d = blk >> 9;
  int t = chunk * 128 + tl;
  int s = d ? (511 - t) : t;
  __shared__ int tok[128];
  int tid = threadIdx.x;
  if (tid < 128) tok[tid] = sentence[tid * SEQ + s];
  __syncthreads();

  int w = tid >> 6, lane = tid & 63;
  int q = lane >> 4, r = lane & 15;
  int wr = w >> 1, wc = w & 1;
  int r0 = wr * 64;
  int c0 = nb * 128 + wc * 64;

  floatx4 acc[4][4];
#pragma unroll
  for (int i = 0; i < 4; ++i)
#pragma unroll
    for (int j = 0; j < 4; ++j) acc[i][j] = (floatx4){0.f, 0.f, 0.f, 0.f};

  const float4* aptr[4];
#pragma unroll
  for (int i = 0; i < 4; ++i)
    aptr[i] = (const float4*)(embed + (size_t)tok[r0 + i * 16 + r] * HID) + q * 2;
  const uint4* bptr[4];
#pragma unroll
  for (int j = 0; j < 4; ++j)
    bptr[j] = (const uint4*)(wihI + ((size_t)d * 512 + c0 + j * 16 + r) * 64) + q;

#pragma unroll
  for (int kc = 0; kc < 4; ++kc) {
    half8_t af[4], bf[4];
#pragma unroll
    for (int i = 0; i < 4; ++i) {
      float4 x0 = aptr[i][kc * 8];
      float4 x1 = aptr[i][kc * 8 + 1];
      uint4 u;
      u.x = packh2(x0.x, x0.y); u.y = packh2(x0.z, x0.w);
      u.z = packh2(x1.x, x1.y); u.w = packh2(x1.z, x1.w);
      af[i] = __builtin_bit_cast(half8_t, u);
    }
#pragma unroll
    for (int j = 0; j < 4; ++j)
      bf[j] = __builtin_bit_cast(half8_t, bptr[j][kc * 4]);
#pragma unroll
    for (int i = 0; i < 4; ++i)
#pragma unroll
      for (int j = 0; j < 4; ++j)
        acc[i][j] = __builtin_amdgcn_mfma_f32_16x16x32_f16(af[i], bf[j], acc[i][j], 0, 0, 0);
  }

  __fp16* gat = ((__fp16*)gatex) + (size_t)d * 16384 * 512;
#pragma unroll
  for (int j = 0; j < 4; ++j) {
    int n = c0 + j * 16 + r;
    float bb = biasI[d * 512 + n];
#pragma unroll
    for (int i = 0; i < 4; ++i) {
      int rb = r0 + i * 16 + q * 4;
#pragma unroll
      for (int reg = 0; reg < 4; ++reg) {
        float v = acc[i][j][reg] + bb;
        gat[((size_t)(tl * 128 + rb + reg)) * 512 + n] = (__fp16)v;
      }
    }
  }
}

// ---------------------------------------------------------------------------
// LSTM recurrence — R11 restructure.
// R8 diagnosis: 256 thr × 128 weight-VGPRs needed, allocator capped at ~84
// (targets ~6 waves/EU) -> ~2/3 of whh re-streamed from L2 every step =
// 2.9 GB/dispatch = ~35 TB/s = L2 ceiling. R10's asm anchors made it spill
// to scratch instead (worse). Fix: halve per-thread weights and pin the
// occupancy target.
//   * 512 threads (8 waves, 2/SIMD). Thread t: kq=t&3 (k-quarter),
//     m=t>>2 (hidden unit). Owns all 4 gate rows of m over 32 k-elems:
//     weights = 16 uint4 = 64 VGPRs.
//   * quad shfl_xor(1),(2) completes the k-reduction; every quad lane then
//     has all 4 gate pre-activations for m (no cross-wave traffic).
//   * amdgpu_waves_per_eu(2,2): VGPR budget 256, occupancy target == what
//     actually runs (1 WG/CU, grid=256). ~110 VGPRs needed -> no reason to
//     sink/spill weight loads.
// Expected: VGPR ~100-130 (verify!), dur ~25-35 us/dispatch.
// ---------------------------------------------------------------------------
__global__ __attribute__((amdgpu_waves_per_eu(2, 2))) __launch_bounds__(512)
void lstm_kernel(
    const uint* __restrict__ gatex, const uint* __restrict__ whh,
    const float* __restrict__ h0, const float* __restrict__ c0,
    float* __restrict__ statec, uint* __restrict__ hh, int chunk)
{
  const int wg = blockIdx.x;
  const int d = wg >> 7, b = wg & 127;
  const int tid = threadIdx.x;
  const int kq = tid & 3, m = tid >> 2;

  __shared__ __align__(16) __fp16 hist[128][128];   // 32 KB

  // Weights: gate g row = g*128+m (64 uints); this thread's quarter = 4 uint4.
  const uint4* wh4 = (const uint4*)whh + (size_t)d * 8192;
  uint4 wreg[4][4];
#pragma unroll
  for (int g = 0; g < 4; ++g) {
    const uint4* row = wh4 + ((size_t)(g * 128 + m)) * 16 + kq * 4;
#pragma unroll
    for (int i = 0; i < 4; ++i) wreg[g][i] = row[i];
  }

  float c = (chunk == 0) ? c0[(size_t)(d * 128 + b) * 128 + m]
                         : statec[(size_t)(d * 128 + b) * 128 + m];

  if (tid < 64) {
    uint* h127 = (uint*)&hist[127][0];
    if (chunk == 0) {
      float2 hv = ((const float2*)(h0 + (size_t)(d * 128 + b) * 128))[tid];
      h127[tid] = packh2(hv.x, hv.y);
    } else {
      int sprev = d ? (511 - (chunk * 128 - 1)) : (chunk * 128 - 1);
      h127[tid] = hh[((size_t)(d * 512 + sprev) * 128 + b) * 64 + tid];
    }
  }
  // Gate-x (input contribution): halfs 4m..4m+3 = (i,f,g,o) for unit m.
  const uint* gx0 = gatex + (size_t)d * 4194304 + (size_t)b * 256 + 2 * m;
  uint2 gx = *(const uint2*)(gx0);
  __syncthreads();

  for (int tl = 0; tl < 128; ++tl) {
    uint2 gxn = gx;
    if (tl < 127) gxn = *(const uint2*)(gx0 + (size_t)(tl + 1) * 32768);

    float a0 = 0.f, a1 = 0.f, a2 = 0.f, a3 = 0.f;
    const uint4* z4 = (const uint4*)(&hist[(tl + 127) & 127][kq * 32]);
#pragma unroll
    for (int i = 0; i < 4; ++i) {
      uint4 z = z4[i];
      a0 = fdot2(z.x, wreg[0][i].x, a0);
      a0 = fdot2(z.y, wreg[0][i].y, a0);
      a0 = fdot2(z.z, wreg[0][i].z, a0);
      a0 = fdot2(z.w, wreg[0][i].w, a0);
      a1 = fdot2(z.x, wreg[1][i].x, a1);
      a1 = fdot2(z.y, wreg[1][i].y, a1);
      a1 = fdot2(z.z, wreg[1][i].z, a1);
      a1 = fdot2(z.w, wreg[1][i].w, a1);
      a2 = fdot2(z.x, wreg[2][i].x, a2);
      a2 = fdot2(z.y, wreg[2][i].y, a2);
      a2 = fdot2(z.z, wreg[2][i].z, a2);
      a2 = fdot2(z.w, wreg[2][i].w, a2);
      a3 = fdot2(z.x, wreg[3][i].x, a3);
      a3 = fdot2(z.y, wreg[3][i].y, a3);
      a3 = fdot2(z.z, wreg[3][i].z, a3);
      a3 = fdot2(z.w, wreg[3][i].w, a3);
    }
    // quad reduction over k-quarters: lanes kq=0..3 share m.
    a0 += __shfl_xor(a0, 1); a0 += __shfl_xor(a0, 2);
    a1 += __shfl_xor(a1, 1); a1 += __shfl_xor(a1, 2);
    a2 += __shfl_xor(a2, 1); a2 += __shfl_xor(a2, 2);
    a3 += __shfl_xor(a3, 1); a3 += __shfl_xor(a3, 2);

    half2_t g01 = __builtin_bit_cast(half2_t, gx.x);
    half2_t g23 = __builtin_bit_cast(half2_t, gx.y);
    a0 += (float)g01[0];
    a1 += (float)g01[1];
    a2 += (float)g23[0];
    a3 += (float)g23[1];

    float ig = fsig(a0);
    float fg = fsig(a1);
    float gg = ftanh(a2);
    float og = fsig(a3);
    c = fg * c + ig * gg;
    float hv = og * ftanh(c);

    if (kq == 0) hist[tl][m] = (__fp16)hv;
    gx = gxn;
    __syncthreads();
  }

  if (kq == 0) statec[(size_t)(d * 128 + b) * 128 + m] = c;

  int base = chunk * 128;
  for (int i = tid; i < 2048; i += 512) {
    int sl = i >> 4, q4 = i & 15;
    int s = d ? (511 - (base + sl)) : (base + sl);
    *(uint4*)(&hh[((size_t)(d * 512 + s) * 128 + b) * 64 + q4 * 4]) =
        *(const uint4*)((const uint*)&hist[sl][0] + q4 * 4);
  }
}

// ---------------------------------------------------------------------------
// Output projection (unchanged from R8)
// ---------------------------------------------------------------------------
__global__ __launch_bounds__(256) void outproj_kernel(
    const uint* __restrict__ hh, const uint* __restrict__ woutp,
    const float* __restrict__ bout, float* __restrict__ feats)
{
  __shared__ __align__(16) uint4 zrow[8][32];
  __shared__ __align__(16) uint4 wlds[32][32];
  int tid = threadIdx.x;
  for (int j = tid; j < 1024; j += 256) {
    int k = j >> 5, i = j & 31;
    wlds[i][k] = ((const uint4*)woutp)[j];
  }
  int rl = tid >> 5, q = tid & 31;
  int row = blockIdx.x * 8 + rl;
  int b = row >> 9, s = row & 511;
  const uint4* hf4 = (const uint4*)(hh + ((size_t)s * BATCH + b) * 64);
  const uint4* hb4 = (const uint4*)(hh + ((size_t)(SEQ + s) * BATCH + b) * 64);
  zrow[rl][q] = (q < 16) ? hf4[q] : hb4[q - 16];
  __syncthreads();
  int k = q;
  float acc = bout[k];
#pragma unroll
  for (int i = 0; i < 32; ++i) {
    uint4 z = zrow[rl][i];
    uint4 wv = wlds[i][k];
    acc = fdot2(z.x, wv.x, acc);
    acc = fdot2(z.y, wv.y, acc);
    acc = fdot2(z.z, wv.z, acc);
    acc = fdot2(z.w, wv.w, acc);
  }
  feats[(size_t)row * 32 + k] = acc;
}

// ---------------------------------------------------------------------------
// CRF numerator (unchanged)
// ---------------------------------------------------------------------------
__global__ __launch_bounds__(64) void crf_num_kernel(
    const int* __restrict__ tags, const float* __restrict__ feats,
    const float* __restrict__ trans, float* __restrict__ num)
{
  int b = blockIdx.x, l = threadIdx.x;
  const int* tb = tags + b * SEQ;
  float acc = 0.f;
  for (int s = l; s < SEQ; s += 64) {
    int tg = tb[s];
    int pv = (s == 0) ? START_TAG : tb[s - 1];
    acc += trans[pv * NTAG + tg] + feats[((size_t)b * SEQ + s) * NTAG + tg];
  }
#pragma unroll
  for (int msk = 1; msk < 64; msk <<= 1) acc += __shfl_xor(acc, msk);
  if (l == 0) num[b] = acc + trans[tb[SEQ - 1] * NTAG + END_TAG];
}

// ---------------------------------------------------------------------------
// CRF stage A (unchanged from R8)
// ---------------------------------------------------------------------------
__global__ __launch_bounds__(64) void crf_seg_kernel(
    const float* __restrict__ feats, const float* __restrict__ trans,
    uint* __restrict__ segP, float* __restrict__ segL)
{
  const float L2E = 1.4426950408889634f;
  int blk = blockIdx.x;
  int b = blk >> 5, j = blk & 31;
  int tstart = 1 + 16 * j;
  int nsteps = (j == 31) ? 15 : 16;
  int lane = threadIdx.x;
  int c = lane & 15, q = lane >> 4;

  half8_t afr[2];
#pragma unroll
  for (int rt = 0; rt < 2; ++rt) {
    const float* trow = trans + (rt * 16 + c) * 32 + q * 8;
    float e[8];
#pragma unroll
    for (int i = 0; i < 8; ++i) e[i] = fexp2(trow[i] * L2E);
    uint4 u;
    u.x = packh2(e[0], e[1]); u.y = packh2(e[2], e[3]);
    u.z = packh2(e[4], e[5]); u.w = packh2(e[6], e[7]);
    afr[rt] = __builtin_bit_cast(half8_t, u);
  }
  half8_t bfr[2];
#pragma unroll
  for (int ct = 0; ct < 2; ++ct) {
    uint4 u;
    uint vals[8];
#pragma unroll
    for (int i = 0; i < 8; ++i)
      vals[i] = ((q * 8 + i) == (ct * 16 + c)) ? 0x3C00u : 0u;
    u.x = vals[0] | (vals[1] << 16);
    u.y = vals[2] | (vals[3] << 16);
    u.z = vals[4] | (vals[5] << 16);
    u.w = vals[6] | (vals[7] << 16);
    bfr[ct] = __builtin_bit_cast(half8_t, u);
  }

  __shared__ __fp16 P16[32 * 36];

  const float* fb = feats + ((size_t)b * SEQ + tstart) * NTAG;
  float Lacc = 0.f;
  float4 pre0 = *(const float4*)(fb + q * 4);
  float4 pre1 = *(const float4*)(fb + 16 + q * 4);

  for (int s = 0; s < nsteps; ++s) {
    float4 f0 = pre0, f1 = pre1;
    if (s + 1 < nsteps) {
      pre0 = *(const float4*)(fb + (s + 1) * 32 + q * 4);
      pre1 = *(const float4*)(fb + (s + 1) * 32 + 16 + q * 4);
    }
    floatx4 z4 = (floatx4){0.f, 0.f, 0.f, 0.f};
    floatx4 c00 = __builtin_amdgcn_mfma_f32_16x16x32_f16(afr[0], bfr[0], z4, 0, 0, 0);
    floatx4 c01 = __builtin_amdgcn_mfma_f32_16x16x32_f16(afr[0], bfr[1], z4, 0, 0, 0);
    floatx4 c10 = __builtin_amdgcn_mfma_f32_16x16x32_f16(afr[1], bfr[0], z4, 0, 0, 0);
    floatx4 c11 = __builtin_amdgcn_mfma_f32_16x16x32_f16(afr[1], bfr[1], z4, 0, 0, 0);
    float pf0[4], pf1[4];
    pf0[0] = fexp2(f0.x * L2E); pf0[1] = fexp2(f0.y * L2E);
    pf0[2] = fexp2(f0.z * L2E); pf0[3] = fexp2(f0.w * L2E);
    pf1[0] = fexp2(f1.x * L2E); pf1[1] = fexp2(f1.y * L2E);
    pf1[2] = fexp2(f1.z * L2E); pf1[3] = fexp2(f1.w * L2E);
    float v00[4], v01[4], v10[4], v11[4];
#pragma unroll
    for (int rg = 0; rg < 4; ++rg) {
      v00[rg] = c00[rg] * pf0[rg];
      v01[rg] = c01[rg] * pf0[rg];
      v10[rg] = c10[rg] * pf1[rg];
      v11[rg] = c11[rg] * pf1[rg];
    }
    float mx = 0.f;
#pragma unroll
    for (int rg = 0; rg < 4; ++rg)
      mx = fmaxf(mx, fmaxf(fmaxf(v00[rg], v01[rg]), fmaxf(v10[rg], v11[rg])));
    uint ub = (uint)__builtin_amdgcn_readfirstlane((int)__builtin_bit_cast(uint, mx));
    int e = (int)((ub >> 23) & 255u);
    Lacc += (float)(e - 127);
    float sc = __builtin_bit_cast(float, (uint)((254 - e) << 23));

    __syncthreads();
    {
      uint2 wv2;
      wv2.x = packh2(v00[0] * sc, v00[1] * sc);
      wv2.y = packh2(v00[2] * sc, v00[3] * sc);
      *(uint2*)(&P16[c * 36 + q * 4]) = wv2;
      wv2.x = packh2(v10[0] * sc, v10[1] * sc);
      wv2.y = packh2(v10[2] * sc, v10[3] * sc);
      *(uint2*)(&P16[c * 36 + 16 + q * 4]) = wv2;
      wv2.x = packh2(v01[0] * sc, v01[1] * sc);
      wv2.y = packh2(v01[2] * sc, v01[3] * sc);
      *(uint2*)(&P16[(16 + c) * 36 + q * 4]) = wv2;
      wv2.x = packh2(v11[0] * sc, v11[1] * sc);
      wv2.y = packh2(v11[2] * sc, v11[3] * sc);
      *(uint2*)(&P16[(16 + c) * 36 + 16 + q * 4]) = wv2;
    }
    __syncthreads();
    {
      uint2 lo0 = *(const uint2*)(&P16[c * 36 + q * 8]);
      uint2 hi0 = *(const uint2*)(&P16[c * 36 + q * 8 + 4]);
      uint4 u0; u0.x = lo0.x; u0.y = lo0.y; u0.z = hi0.x; u0.w = hi0.y;
      bfr[0] = __builtin_bit_cast(half8_t, u0);
      uint2 lo1 = *(const uint2*)(&P16[(16 + c) * 36 + q * 8]);
      uint2 hi1 = *(const uint2*)(&P16[(16 + c) * 36 + q * 8 + 4]);
      uint4 u1; u1.x = lo1.x; u1.y = lo1.y; u1.z = hi1.x; u1.w = hi1.y;
      bfr[1] = __builtin_bit_cast(half8_t, u1);
    }
  }
  __syncthreads();
  uint* gp = segP + (size_t)blk * 512;
  if (lane < 32) {
    int i = lane;
#pragma unroll
    for (int tp = 0; tp < 16; ++tp) {
      uint lo = (uint)__builtin_bit_cast(unsigned short, P16[(2 * tp) * 36 + i]);
      uint hi = (uint)__builtin_bit_cast(unsigned short, P16[(2 * tp + 1) * 36 + i]);
      gp[i * 16 + tp] = lo | (hi << 16);
    }
  }
  if (lane == 0) segL[blk] = Lacc;
}

// ---------------------------------------------------------------------------
// CRF stage B (unchanged from R8)
// ---------------------------------------------------------------------------
__global__ __launch_bounds__(64) void crf_comb_kernel(
    const float* __restrict__ feats, const float* __restrict__ trans,
    const uint* __restrict__ segP, const float* __restrict__ segL,
    float* __restrict__ den)
{
  const float L2E = 1.4426950408889634f, LN2 = 0.6931471805599453f;
  int b = blockIdx.x, l = threadIdx.x;
  int i = l & 31, hp = l >> 5;
  const float* fb = feats + (size_t)b * SEQ * NTAG;

  float sT = 0.f;
  for (int p = 0; p < 32; ++p) sT += fexp2(trans[i * 32 + p] * L2E);
  float v = (1.f + sT) * fexp2(fb[i] * L2E);
  float L = -10000.f * L2E;

  float vo = __shfl_xor(v, 1);
  uint pv = (i & 1) ? packh2(vo, v) : packh2(v, vo);

  const uint* gp0 = segP + (size_t)b * 32 * 512 + i * 16 + hp * 8;
  uint4 ra = *(const uint4*)(gp0);
  uint4 rb = *(const uint4*)(gp0 + 4);

  for (int seg = 0; seg < 32; ++seg) {
    uint4 ca = ra, cb = rb;
    if (seg + 1 < 32) {
      ra = *(const uint4*)(gp0 + (seg + 1) * 512);
      rb = *(const uint4*)(gp0 + (seg + 1) * 512 + 4);
    }
    float g0 = __shfl(__builtin_bit_cast(float, pv), hp * 16 + 0);
    float g1 = __shfl(__builtin_bit_cast(float, pv), hp * 16 + 2);
    float g2 = __shfl(__builtin_bit_cast(float, pv), hp * 16 + 4);
    float g3 = __shfl(__builtin_bit_cast(float, pv), hp * 16 + 6);
    float g4 = __shfl(__builtin_bit_cast(float, pv), hp * 16 + 8);
    float g5 = __shfl(__builtin_bit_cast(float, pv), hp * 16 + 10);
    float g6 = __shfl(__builtin_bit_cast(float, pv), hp * 16 + 12);
    float g7 = __shfl(__builtin_bit_cast(float, pv), hp * 16 + 14);
    float acc = 0.f;
    acc = fdot2(__builtin_bit_cast(uint, g0), ca.x, acc);
    acc = fdot2(__builtin_bit_cast(uint, g1), ca.y, acc);
    acc = fdot2(__builtin_bit_cast(uint, g2), ca.z, acc);
    acc = fdot2(__builtin_bit_cast(uint, g3), ca.w, acc);
    acc = fdot2(__builtin_bit_cast(uint, g4), cb.x, acc);
    acc = fdot2(__builtin_bit_cast(uint, g5), cb.y, acc);
    acc = fdot2(__builtin_bit_cast(uint, g6), cb.z, acc);
    acc = fdot2(__builtin_bit_cast(uint, g7), cb.w, acc);
    float sm = acc + __shfl_xor(acc, 32);
    uint ub = (uint)__builtin_amdgcn_readfirstlane((int)__builtin_bit_cast(uint, sm));
    int e = (int)((ub >> 23) & 255u);
    L += (float)(e - 127) + segL[b * 32 + seg];
    float sc = __builtin_bit_cast(float, (uint)((254 - e) << 23));
    v = sm * sc;
    float vo2 = __shfl_xor(v, 1);
    pv = (i & 1) ? packh2(vo2, v) : packh2(v, vo2);
  }
  float wv = v * fexp2(trans[i * 32 + END_TAG] * L2E);
#pragma unroll
  for (int msk = 1; msk <= 16; msk <<= 1) wv += __shfl_xor(wv, msk);
  if (l == 0) den[b] = (L + flog2(wv)) * LN2;
}

__global__ __launch_bounds__(128) void final_kernel(
    const float* __restrict__ num, const float* __restrict__ den,
    float* __restrict__ out)
{
  int tid = threadIdx.x;
  float v = num[tid] - den[tid];
#pragma unroll
  for (int msk = 1; msk < 64; msk <<= 1) v += __shfl_xor(v, msk);
  __shared__ float tmp[2];
  if ((tid & 63) == 0) tmp[tid >> 6] = v;
  __syncthreads();
  if (tid == 0) out[0] = (tmp[0] + tmp[1]) * (1.f / 128.f);
}

// ---------------------------------------------------------------------------
// Workspace layout (bytes): same as R8 (~51.4 MB named; gatex tail overlaps
// the later-phase buffers deliberately — gatex is dead after the chunk loop)
// ---------------------------------------------------------------------------
extern "C" void kernel_launch(void* const* d_in, const int* in_sizes, int n_in,
                              void* d_out, int out_size, void* d_ws, size_t ws_size,
                              hipStream_t stream)
{
  const int* sentence = (const int*)d_in[0];
  const int* tags = (const int*)d_in[1];
  const float* embed = (const float*)d_in[2];
  const float* Wihf = (const float*)d_in[3];
  const float* Whhf = (const float*)d_in[4];
  const float* bihf = (const float*)d_in[5];
  const float* bhhf = (const float*)d_in[6];
  const float* Wihb = (const float*)d_in[7];
  const float* Whhb = (const float*)d_in[8];
  const float* bihb = (const float*)d_in[9];
  const float* bhhb = (const float*)d_in[10];
  const float* Wout = (const float*)d_in[11];
  const float* bout = (const float*)d_in[12];
  const float* trans = (const float*)d_in[13];
  const float* h0 = (const float*)d_in[14];
  const float* c0 = (const float*)d_in[15];
  float* out = (float*)d_out;

  char* ws = (char*)d_ws;
  uint* wihI = (uint*)(ws + 0);
  uint* whh = (uint*)(ws + 262144);
  uint* woutp = (uint*)(ws + 524288);
  float* biasI = (float*)(ws + 540672);
  float* numb = (float*)(ws + 544768);
  float* denb = (float*)(ws + 545280);
  float* statec = (float*)(ws + 545792);
  uint* hh = (uint*)(ws + 1048576);
  uint* gatex = (uint*)(ws + 34603008);
  float* feats = (float*)(ws + 34603008);
  uint* segP = (uint*)(ws + 42991616);
  float* segL = (float*)(ws + 51380224);

  hipLaunchKernelGGL(prep_kernel, dim3(532), dim3(256), 0, stream,
                     Wihf, Whhf, bihf, bhhf, Wihb, Whhb, bihb, bhhb, Wout,
                     wihI, whh, woutp, biasI);
  for (int c = 0; c < 4; ++c) {
    hipLaunchKernelGGL(gemmx_kernel, dim3(1024), dim3(256), 0, stream,
                       sentence, embed, wihI, biasI, gatex, c);
    hipLaunchKernelGGL(lstm_kernel, dim3(256), dim3(512), 0, stream,
                       gatex, whh, h0, c0, statec, hh, c);
  }
  hipLaunchKernelGGL(outproj_kernel, dim3(8192), dim3(256), 0, stream,
                     hh, woutp, bout, feats);
  hipLaunchKernelGGL(crf_num_kernel, dim3(128), dim3(64), 0, stream,
                     tags, feats, trans, numb);
  hipLaunchKernelGGL(crf_seg_kernel, dim3(4096), dim3(64), 0, stream,
                     feats, trans, segP, segL);
  hipLaunchKernelGGL(crf_comb_kernel, dim3(128), dim3(64), 0, stream,
                     feats, trans, segP, segL, denb);
  hipLaunchKernelGGL(final_kernel, dim3(1), dim3(128), 0, stream,
                     numb, denb, out);
}

// Round 4
// 595.203 us; speedup vs baseline: 1.1531x; 1.0538x over previous
//
#include <hip/hip_runtime.h>

typedef unsigned int uint;
typedef __fp16 half2_t __attribute__((ext_vector_type(2)));
typedef __fp16 half8_t __attribute__((ext_vector_type(8)));
typedef float floatx4 __attribute__((ext_vector_type(4)));

#define SEQ 512
#define BATCH 128
#define HID 128
#define NTAG 32
#define START_TAG 30
#define END_TAG 31

__device__ __forceinline__ float fdot2(uint a, uint b, float c) {
  return __builtin_amdgcn_fdot2(__builtin_bit_cast(half2_t, a),
                                __builtin_bit_cast(half2_t, b), c, false);
}
__device__ __forceinline__ uint packh2(float a, float b) {
  half2_t h = __builtin_amdgcn_cvt_pkrtz(a, b);
  return __builtin_bit_cast(uint, h);
}
__device__ __forceinline__ float frcp(float x) { return __builtin_amdgcn_rcpf(x); }
__device__ __forceinline__ float fsig(float x) { return frcp(1.f + __expf(-x)); }
__device__ __forceinline__ float ftanh(float x) { return 1.f - 2.f * frcp(1.f + __expf(2.f * x)); }
__device__ __forceinline__ float fexp2(float x) { return __builtin_amdgcn_exp2f(x); }
__device__ __forceinline__ float flog2(float x) { return __builtin_amdgcn_logf(x); }

// Quad butterfly sum via DPP quad_perm (VALU pipe, no LDS):
// 0xB1 = quad_perm[1,0,3,2] (xor 1), 0x4E = quad_perm[2,3,0,1] (xor 2).
// Uses the supported update_dpp builtin (mov_dpp is deprecated).
__device__ __forceinline__ float quad_add(float x) {
  int a = __builtin_bit_cast(int, x);
  int b = __builtin_amdgcn_update_dpp(0, a, 0xB1, 0xF, 0xF, true);
  float y = x + __builtin_bit_cast(float, b);
  int c2 = __builtin_bit_cast(int, y);
  int d2 = __builtin_amdgcn_update_dpp(0, c2, 0x4E, 0xF, 0xF, true);
  return y + __builtin_bit_cast(float, d2);
}

// ---------------------------------------------------------------------------
// prep (unchanged from R8)
// ---------------------------------------------------------------------------
__global__ __launch_bounds__(256) void prep_kernel(
    const float* __restrict__ Wihf, const float* __restrict__ Whhf,
    const float* __restrict__ bihf, const float* __restrict__ bhhf,
    const float* __restrict__ Wihb, const float* __restrict__ Whhb,
    const float* __restrict__ bihb, const float* __restrict__ bhhb,
    const float* __restrict__ Wout,
    uint* __restrict__ wihI, uint* __restrict__ whh,
    uint* __restrict__ woutp, float* __restrict__ biasI)
{
  int idx = blockIdx.x * 256 + threadIdx.x;
  if (idx < 65536) {
    int d = idx >> 15, rem = idx & 32767;
    int n = rem >> 6, dw = rem & 63;
    int m = n >> 2, q = n & 3;
    int g = q * 128 + m;
    const float* W = d ? Wihb : Wihf;
    wihI[idx] = packh2(W[g * 128 + 2 * dw], W[g * 128 + 2 * dw + 1]);
  }
  int i2 = idx - 65536;
  if (i2 >= 0 && i2 < 65536) {
    int d = i2 >> 15, rem = i2 & 32767;
    int g = rem >> 6, dw = rem & 63;
    const float* W = d ? Whhb : Whhf;
    whh[i2] = packh2(W[g * 128 + 2 * dw], W[g * 128 + 2 * dw + 1]);
  }
  int i3 = idx - 131072;
  if (i3 >= 0 && i3 < 4096) {
    int k = i3 >> 7, dw = i3 & 127;
    float a, b2;
    if (dw < 64) { a = Wout[k * 256 + 2 * dw]; b2 = Wout[k * 256 + 2 * dw + 1]; }
    else { int j = dw - 64; a = Wout[k * 256 + 128 + 2 * j]; b2 = Wout[k * 256 + 128 + 2 * j + 1]; }
    woutp[i3] = packh2(a, b2);
  }
  int i4 = idx - 135168;
  if (i4 >= 0 && i4 < 1024) {
    int d = i4 >> 9, n = i4 & 511;
    int g = (n & 3) * 128 + (n >> 2);
    biasI[i4] = d ? (bihb[g] + bhhb[g]) : (bihf[g] + bhhf[g]);
  }
}

// ---------------------------------------------------------------------------
// gemmx (unchanged from R8)
// ---------------------------------------------------------------------------
__global__ __launch_bounds__(256, 2) void gemmx_kernel(
    const int* __restrict__ sentence, const float* __restrict__ embed,
    const uint* __restrict__ wihI, const float* __restrict__ biasI,
    uint* __restrict__ gatex, int chunk)
{
  int blk = blockIdx.x;
  int tl = blk & 127, nb = (blk >> 7) & 3, d = blk >> 9;
  int t = chunk * 128 + tl;
  int s = d ? (511 - t) : t;
  __shared__ int tok[128];
  int tid = threadIdx.x;
  if (tid < 128) tok[tid] = sentence[tid * SEQ + s];
  __syncthreads();

  int w = tid >> 6, lane = tid & 63;
  int q = lane >> 4, r = lane & 15;
  int wr = w >> 1, wc = w & 1;
  int r0 = wr * 64;
  int c0 = nb * 128 + wc * 64;

  floatx4 acc[4][4];
#pragma unroll
  for (int i = 0; i < 4; ++i)
#pragma unroll
    for (int j = 0; j < 4; ++j) acc[i][j] = (floatx4){0.f, 0.f, 0.f, 0.f};

  const float4* aptr[4];
#pragma unroll
  for (int i = 0; i < 4; ++i)
    aptr[i] = (const float4*)(embed + (size_t)tok[r0 + i * 16 + r] * HID) + q * 2;
  const uint4* bptr[4];
#pragma unroll
  for (int j = 0; j < 4; ++j)
    bptr[j] = (const uint4*)(wihI + ((size_t)d * 512 + c0 + j * 16 + r) * 64) + q;

#pragma unroll
  for (int kc = 0; kc < 4; ++kc) {
    half8_t af[4], bf[4];
#pragma unroll
    for (int i = 0; i < 4; ++i) {
      float4 x0 = aptr[i][kc * 8];
      float4 x1 = aptr[i][kc * 8 + 1];
      uint4 u;
      u.x = packh2(x0.x, x0.y); u.y = packh2(x0.z, x0.w);
      u.z = packh2(x1.x, x1.y); u.w = packh2(x1.z, x1.w);
      af[i] = __builtin_bit_cast(half8_t, u);
    }
#pragma unroll
    for (int j = 0; j < 4; ++j)
      bf[j] = __builtin_bit_cast(half8_t, bptr[j][kc * 4]);
#pragma unroll
    for (int i = 0; i < 4; ++i)
#pragma unroll
      for (int j = 0; j < 4; ++j)
        acc[i][j] = __builtin_amdgcn_mfma_f32_16x16x32_f16(af[i], bf[j], acc[i][j], 0, 0, 0);
  }

  __fp16* gat = ((__fp16*)gatex) + (size_t)d * 16384 * 512;
#pragma unroll
  for (int j = 0; j < 4; ++j) {
    int n = c0 + j * 16 + r;
    float bb = biasI[d * 512 + n];
#pragma unroll
    for (int i = 0; i < 4; ++i) {
      int rb = r0 + i * 16 + q * 4;
#pragma unroll
      for (int reg = 0; reg < 4; ++reg) {
        float v = acc[i][j][reg] + bb;
        gat[((size_t)(tl * 128 + rb + reg)) * 512 + n] = (__fp16)v;
      }
    }
  }
}

// ---------------------------------------------------------------------------
// LSTM recurrence — R13 (= R12 design, update_dpp builtin).
// R11 post-mortem: weights resident (VGPR 88) but 96us > R8's 82.6 ->
// critical path is NOT weight traffic. The 8 __shfl_xor(1/2) lower to
// ds_swizzle_b32 = LDS pipe: 64 wave-wide DS ops/step (~370 cyc pipe
// occupancy) + 2 serial ~120cyc latencies per step, on top of hist
// ds_reads + barrier. Fixes:
//  * quad reduce via DPP quad_perm (VALU, ~2cyc, no LDS pipe) - quad_add().
//  * gatex prefetch deepened 1 -> 4 steps (register ring, unroll-4, static
//    indices) to cover ~900cyc HBM miss latency.
// Expected: dur 96 -> 55-70us, VALUBusy -> 70-85%, VGPR ~100.
// ---------------------------------------------------------------------------
__global__ __attribute__((amdgpu_waves_per_eu(2, 2))) __launch_bounds__(512)
void lstm_kernel(
    const uint* __restrict__ gatex, const uint* __restrict__ whh,
    const float* __restrict__ h0, const float* __restrict__ c0,
    float* __restrict__ statec, uint* __restrict__ hh, int chunk)
{
  const int wg = blockIdx.x;
  const int d = wg >> 7, b = wg & 127;
  const int tid = threadIdx.x;
  const int kq = tid & 3, m = tid >> 2;

  __shared__ __align__(16) __fp16 hist[128][128];   // 32 KB

  // Weights: gate g row = g*128+m (64 uints); this thread's quarter = 4 uint4.
  const uint4* wh4 = (const uint4*)whh + (size_t)d * 8192;
  uint4 wreg[4][4];
#pragma unroll
  for (int g = 0; g < 4; ++g) {
    const uint4* row = wh4 + ((size_t)(g * 128 + m)) * 16 + kq * 4;
#pragma unroll
    for (int i = 0; i < 4; ++i) wreg[g][i] = row[i];
  }

  float c = (chunk == 0) ? c0[(size_t)(d * 128 + b) * 128 + m]
                         : statec[(size_t)(d * 128 + b) * 128 + m];

  if (tid < 64) {
    uint* h127 = (uint*)&hist[127][0];
    if (chunk == 0) {
      float2 hv = ((const float2*)(h0 + (size_t)(d * 128 + b) * 128))[tid];
      h127[tid] = packh2(hv.x, hv.y);
    } else {
      int sprev = d ? (511 - (chunk * 128 - 1)) : (chunk * 128 - 1);
      h127[tid] = hh[((size_t)(d * 512 + sprev) * 128 + b) * 64 + tid];
    }
  }
  // Gate-x (input contribution): halfs 4m..4m+3 = (i,f,g,o) for unit m.
  const uint* gx0 = gatex + (size_t)d * 4194304 + (size_t)b * 256 + 2 * m;

  // One LSTM step: consume gate-x gxc at timestep tl_.
  auto step = [&](int tl_, uint2 gxc) {
    float a0 = 0.f, a1 = 0.f, a2 = 0.f, a3 = 0.f;
    const uint4* z4 = (const uint4*)(&hist[(tl_ + 127) & 127][kq * 32]);
#pragma unroll
    for (int i = 0; i < 4; ++i) {
      uint4 z = z4[i];
      a0 = fdot2(z.x, wreg[0][i].x, a0);
      a0 = fdot2(z.y, wreg[0][i].y, a0);
      a0 = fdot2(z.z, wreg[0][i].z, a0);
      a0 = fdot2(z.w, wreg[0][i].w, a0);
      a1 = fdot2(z.x, wreg[1][i].x, a1);
      a1 = fdot2(z.y, wreg[1][i].y, a1);
      a1 = fdot2(z.z, wreg[1][i].z, a1);
      a1 = fdot2(z.w, wreg[1][i].w, a1);
      a2 = fdot2(z.x, wreg[2][i].x, a2);
      a2 = fdot2(z.y, wreg[2][i].y, a2);
      a2 = fdot2(z.z, wreg[2][i].z, a2);
      a2 = fdot2(z.w, wreg[2][i].w, a2);
      a3 = fdot2(z.x, wreg[3][i].x, a3);
      a3 = fdot2(z.y, wreg[3][i].y, a3);
      a3 = fdot2(z.z, wreg[3][i].z, a3);
      a3 = fdot2(z.w, wreg[3][i].w, a3);
    }
    // quad butterfly over k-quarters (DPP, VALU-only).
    a0 = quad_add(a0);
    a1 = quad_add(a1);
    a2 = quad_add(a2);
    a3 = quad_add(a3);

    half2_t g01 = __builtin_bit_cast(half2_t, gxc.x);
    half2_t g23 = __builtin_bit_cast(half2_t, gxc.y);
    a0 += (float)g01[0];
    a1 += (float)g01[1];
    a2 += (float)g23[0];
    a3 += (float)g23[1];

    float ig = fsig(a0);
    float fg = fsig(a1);
    float gg = ftanh(a2);
    float og = fsig(a3);
    c = fg * c + ig * gg;
    float hv = og * ftanh(c);

    if (kq == 0) hist[tl_][m] = (__fp16)hv;
    __syncthreads();
  };

  // 4-deep gate-x prefetch ring (static indices; ~4-step HBM hiding window).
  uint2 g0 = *(const uint2*)(gx0);
  uint2 g1 = *(const uint2*)(gx0 + (size_t)1 * 32768);
  uint2 g2 = *(const uint2*)(gx0 + (size_t)2 * 32768);
  uint2 g3 = *(const uint2*)(gx0 + (size_t)3 * 32768);
  __syncthreads();

  for (int tl = 0; tl < 128; tl += 4) {
    int i0 = tl + 4 > 127 ? 127 : tl + 4;
    int i1 = tl + 5 > 127 ? 127 : tl + 5;
    int i2 = tl + 6 > 127 ? 127 : tl + 6;
    int i3 = tl + 7 > 127 ? 127 : tl + 7;
    uint2 n0 = *(const uint2*)(gx0 + (size_t)i0 * 32768);
    uint2 n1 = *(const uint2*)(gx0 + (size_t)i1 * 32768);
    uint2 n2 = *(const uint2*)(gx0 + (size_t)i2 * 32768);
    uint2 n3 = *(const uint2*)(gx0 + (size_t)i3 * 32768);
    step(tl + 0, g0);
    step(tl + 1, g1);
    step(tl + 2, g2);
    step(tl + 3, g3);
    g0 = n0; g1 = n1; g2 = n2; g3 = n3;
  }

  if (kq == 0) statec[(size_t)(d * 128 + b) * 128 + m] = c;

  int base = chunk * 128;
  for (int i = tid; i < 2048; i += 512) {
    int sl = i >> 4, q4 = i & 15;
    int s = d ? (511 - (base + sl)) : (base + sl);
    *(uint4*)(&hh[((size_t)(d * 512 + s) * 128 + b) * 64 + q4 * 4]) =
        *(const uint4*)((const uint*)&hist[sl][0] + q4 * 4);
  }
}

// ---------------------------------------------------------------------------
// Output projection (unchanged from R8)
// ---------------------------------------------------------------------------
__global__ __launch_bounds__(256) void outproj_kernel(
    const uint* __restrict__ hh, const uint* __restrict__ woutp,
    const float* __restrict__ bout, float* __restrict__ feats)
{
  __shared__ __align__(16) uint4 zrow[8][32];
  __shared__ __align__(16) uint4 wlds[32][32];
  int tid = threadIdx.x;
  for (int j = tid; j < 1024; j += 256) {
    int k = j >> 5, i = j & 31;
    wlds[i][k] = ((const uint4*)woutp)[j];
  }
  int rl = tid >> 5, q = tid & 31;
  int row = blockIdx.x * 8 + rl;
  int b = row >> 9, s = row & 511;
  const uint4* hf4 = (const uint4*)(hh + ((size_t)s * BATCH + b) * 64);
  const uint4* hb4 = (const uint4*)(hh + ((size_t)(SEQ + s) * BATCH + b) * 64);
  zrow[rl][q] = (q < 16) ? hf4[q] : hb4[q - 16];
  __syncthreads();
  int k = q;
  float acc = bout[k];
#pragma unroll
  for (int i = 0; i < 32; ++i) {
    uint4 z = zrow[rl][i];
    uint4 wv = wlds[i][k];
    acc = fdot2(z.x, wv.x, acc);
    acc = fdot2(z.y, wv.y, acc);
    acc = fdot2(z.z, wv.z, acc);
    acc = fdot2(z.w, wv.w, acc);
  }
  feats[(size_t)row * 32 + k] = acc;
}

// ---------------------------------------------------------------------------
// CRF numerator (unchanged)
// ---------------------------------------------------------------------------
__global__ __launch_bounds__(64) void crf_num_kernel(
    const int* __restrict__ tags, const float* __restrict__ feats,
    const float* __restrict__ trans, float* __restrict__ num)
{
  int b = blockIdx.x, l = threadIdx.x;
  const int* tb = tags + b * SEQ;
  float acc = 0.f;
  for (int s = l; s < SEQ; s += 64) {
    int tg = tb[s];
    int pv = (s == 0) ? START_TAG : tb[s - 1];
    acc += trans[pv * NTAG + tg] + feats[((size_t)b * SEQ + s) * NTAG + tg];
  }
#pragma unroll
  for (int msk = 1; msk < 64; msk <<= 1) acc += __shfl_xor(acc, msk);
  if (l == 0) num[b] = acc + trans[tb[SEQ - 1] * NTAG + END_TAG];
}

// ---------------------------------------------------------------------------
// CRF stage A (unchanged from R8)
// ---------------------------------------------------------------------------
__global__ __launch_bounds__(64) void crf_seg_kernel(
    const float* __restrict__ feats, const float* __restrict__ trans,
    uint* __restrict__ segP, float* __restrict__ segL)
{
  const float L2E = 1.4426950408889634f;
  int blk = blockIdx.x;
  int b = blk >> 5, j = blk & 31;
  int tstart = 1 + 16 * j;
  int nsteps = (j == 31) ? 15 : 16;
  int lane = threadIdx.x;
  int c = lane & 15, q = lane >> 4;

  half8_t afr[2];
#pragma unroll
  for (int rt = 0; rt < 2; ++rt) {
    const float* trow = trans + (rt * 16 + c) * 32 + q * 8;
    float e[8];
#pragma unroll
    for (int i = 0; i < 8; ++i) e[i] = fexp2(trow[i] * L2E);
    uint4 u;
    u.x = packh2(e[0], e[1]); u.y = packh2(e[2], e[3]);
    u.z = packh2(e[4], e[5]); u.w = packh2(e[6], e[7]);
    afr[rt] = __builtin_bit_cast(half8_t, u);
  }
  half8_t bfr[2];
#pragma unroll
  for (int ct = 0; ct < 2; ++ct) {
    uint4 u;
    uint vals[8];
#pragma unroll
    for (int i = 0; i < 8; ++i)
      vals[i] = ((q * 8 + i) == (ct * 16 + c)) ? 0x3C00u : 0u;
    u.x = vals[0] | (vals[1] << 16);
    u.y = vals[2] | (vals[3] << 16);
    u.z = vals[4] | (vals[5] << 16);
    u.w = vals[6] | (vals[7] << 16);
    bfr[ct] = __builtin_bit_cast(half8_t, u);
  }

  __shared__ __fp16 P16[32 * 36];

  const float* fb = feats + ((size_t)b * SEQ + tstart) * NTAG;
  float Lacc = 0.f;
  float4 pre0 = *(const float4*)(fb + q * 4);
  float4 pre1 = *(const float4*)(fb + 16 + q * 4);

  for (int s = 0; s < nsteps; ++s) {
    float4 f0 = pre0, f1 = pre1;
    if (s + 1 < nsteps) {
      pre0 = *(const float4*)(fb + (s + 1) * 32 + q * 4);
      pre1 = *(const float4*)(fb + (s + 1) * 32 + 16 + q * 4);
    }
    floatx4 z4 = (floatx4){0.f, 0.f, 0.f, 0.f};
    floatx4 c00 = __builtin_amdgcn_mfma_f32_16x16x32_f16(afr[0], bfr[0], z4, 0, 0, 0);
    floatx4 c01 = __builtin_amdgcn_mfma_f32_16x16x32_f16(afr[0], bfr[1], z4, 0, 0, 0);
    floatx4 c10 = __builtin_amdgcn_mfma_f32_16x16x32_f16(afr[1], bfr[0], z4, 0, 0, 0);
    floatx4 c11 = __builtin_amdgcn_mfma_f32_16x16x32_f16(afr[1], bfr[1], z4, 0, 0, 0);
    float pf0[4], pf1[4];
    pf0[0] = fexp2(f0.x * L2E); pf0[1] = fexp2(f0.y * L2E);
    pf0[2] = fexp2(f0.z * L2E); pf0[3] = fexp2(f0.w * L2E);
    pf1[0] = fexp2(f1.x * L2E); pf1[1] = fexp2(f1.y * L2E);
    pf1[2] = fexp2(f1.z * L2E); pf1[3] = fexp2(f1.w * L2E);
    float v00[4], v01[4], v10[4], v11[4];
#pragma unroll
    for (int rg = 0; rg < 4; ++rg) {
      v00[rg] = c00[rg] * pf0[rg];
      v01[rg] = c01[rg] * pf0[rg];
      v10[rg] = c10[rg] * pf1[rg];
      v11[rg] = c11[rg] * pf1[rg];
    }
    float mx = 0.f;
#pragma unroll
    for (int rg = 0; rg < 4; ++rg)
      mx = fmaxf(mx, fmaxf(fmaxf(v00[rg], v01[rg]), fmaxf(v10[rg], v11[rg])));
    uint ub = (uint)__builtin_amdgcn_readfirstlane((int)__builtin_bit_cast(uint, mx));
    int e = (int)((ub >> 23) & 255u);
    Lacc += (float)(e - 127);
    float sc = __builtin_bit_cast(float, (uint)((254 - e) << 23));

    __syncthreads();
    {
      uint2 wv2;
      wv2.x = packh2(v00[0] * sc, v00[1] * sc);
      wv2.y = packh2(v00[2] * sc, v00[3] * sc);
      *(uint2*)(&P16[c * 36 + q * 4]) = wv2;
      wv2.x = packh2(v10[0] * sc, v10[1] * sc);
      wv2.y = packh2(v10[2] * sc, v10[3] * sc);
      *(uint2*)(&P16[c * 36 + 16 + q * 4]) = wv2;
      wv2.x = packh2(v01[0] * sc, v01[1] * sc);
      wv2.y = packh2(v01[2] * sc, v01[3] * sc);
      *(uint2*)(&P16[(16 + c) * 36 + q * 4]) = wv2;
      wv2.x = packh2(v11[0] * sc, v11[1] * sc);
      wv2.y = packh2(v11[2] * sc, v11[3] * sc);
      *(uint2*)(&P16[(16 + c) * 36 + 16 + q * 4]) = wv2;
    }
    __syncthreads();
    {
      uint2 lo0 = *(const uint2*)(&P16[c * 36 + q * 8]);
      uint2 hi0 = *(const uint2*)(&P16[c * 36 + q * 8 + 4]);
      uint4 u0; u0.x = lo0.x; u0.y = lo0.y; u0.z = hi0.x; u0.w = hi0.y;
      bfr[0] = __builtin_bit_cast(half8_t, u0);
      uint2 lo1 = *(const uint2*)(&P16[(16 + c) * 36 + q * 8]);
      uint2 hi1 = *(const uint2*)(&P16[(16 + c) * 36 + q * 8 + 4]);
      uint4 u1; u1.x = lo1.x; u1.y = lo1.y; u1.z = hi1.x; u1.w = hi1.y;
      bfr[1] = __builtin_bit_cast(half8_t, u1);
    }
  }
  __syncthreads();
  uint* gp = segP + (size_t)blk * 512;
  if (lane < 32) {
    int i = lane;
#pragma unroll
    for (int tp = 0; tp < 16; ++tp) {
      uint lo = (uint)__builtin_bit_cast(unsigned short, P16[(2 * tp) * 36 + i]);
      uint hi = (uint)__builtin_bit_cast(unsigned short, P16[(2 * tp + 1) * 36 + i]);
      gp[i * 16 + tp] = lo | (hi << 16);
    }
  }
  if (lane == 0) segL[blk] = Lacc;
}

// ---------------------------------------------------------------------------
// CRF stage B (unchanged from R8)
// ---------------------------------------------------------------------------
__global__ __launch_bounds__(64) void crf_comb_kernel(
    const float* __restrict__ feats, const float* __restrict__ trans,
    const uint* __restrict__ segP, const float* __restrict__ segL,
    float* __restrict__ den)
{
  const float L2E = 1.4426950408889634f, LN2 = 0.6931471805599453f;
  int b = blockIdx.x, l = threadIdx.x;
  int i = l & 31, hp = l >> 5;
  const float* fb = feats + (size_t)b * SEQ * NTAG;

  float sT = 0.f;
  for (int p = 0; p < 32; ++p) sT += fexp2(trans[i * 32 + p] * L2E);
  float v = (1.f + sT) * fexp2(fb[i] * L2E);
  float L = -10000.f * L2E;

  float vo = __shfl_xor(v, 1);
  uint pv = (i & 1) ? packh2(vo, v) : packh2(v, vo);

  const uint* gp0 = segP + (size_t)b * 32 * 512 + i * 16 + hp * 8;
  uint4 ra = *(const uint4*)(gp0);
  uint4 rb = *(const uint4*)(gp0 + 4);

  for (int seg = 0; seg < 32; ++seg) {
    uint4 ca = ra, cb = rb;
    if (seg + 1 < 32) {
      ra = *(const uint4*)(gp0 + (seg + 1) * 512);
      rb = *(const uint4*)(gp0 + (seg + 1) * 512 + 4);
    }
    float g0 = __shfl(__builtin_bit_cast(float, pv), hp * 16 + 0);
    float g1 = __shfl(__builtin_bit_cast(float, pv), hp * 16 + 2);
    float g2 = __shfl(__builtin_bit_cast(float, pv), hp * 16 + 4);
    float g3 = __shfl(__builtin_bit_cast(float, pv), hp * 16 + 6);
    float g4 = __shfl(__builtin_bit_cast(float, pv), hp * 16 + 8);
    float g5 = __shfl(__builtin_bit_cast(float, pv), hp * 16 + 10);
    float g6 = __shfl(__builtin_bit_cast(float, pv), hp * 16 + 12);
    float g7 = __shfl(__builtin_bit_cast(float, pv), hp * 16 + 14);
    float acc = 0.f;
    acc = fdot2(__builtin_bit_cast(uint, g0), ca.x, acc);
    acc = fdot2(__builtin_bit_cast(uint, g1), ca.y, acc);
    acc = fdot2(__builtin_bit_cast(uint, g2), ca.z, acc);
    acc = fdot2(__builtin_bit_cast(uint, g3), ca.w, acc);
    acc = fdot2(__builtin_bit_cast(uint, g4), cb.x, acc);
    acc = fdot2(__builtin_bit_cast(uint, g5), cb.y, acc);
    acc = fdot2(__builtin_bit_cast(uint, g6), cb.z, acc);
    acc = fdot2(__builtin_bit_cast(uint, g7), cb.w, acc);
    float sm = acc + __shfl_xor(acc, 32);
    uint ub = (uint)__builtin_amdgcn_readfirstlane((int)__builtin_bit_cast(uint, sm));
    int e = (int)((ub >> 23) & 255u);
    L += (float)(e - 127) + segL[b * 32 + seg];
    float sc = __builtin_bit_cast(float, (uint)((254 - e) << 23));
    v = sm * sc;
    float vo2 = __shfl_xor(v, 1);
    pv = (i & 1) ? packh2(vo2, v) : packh2(v, vo2);
  }
  float wv = v * fexp2(trans[i * 32 + END_TAG] * L2E);
#pragma unroll
  for (int msk = 1; msk <= 16; msk <<= 1) wv += __shfl_xor(wv, msk);
  if (l == 0) den[b] = (L + flog2(wv)) * LN2;
}

__global__ __launch_bounds__(128) void final_kernel(
    const float* __restrict__ num, const float* __restrict__ den,
    float* __restrict__ out)
{
  int tid = threadIdx.x;
  float v = num[tid] - den[tid];
#pragma unroll
  for (int msk = 1; msk < 64; msk <<= 1) v += __shfl_xor(v, msk);
  __shared__ float tmp[2];
  if ((tid & 63) == 0) tmp[tid >> 6] = v;
  __syncthreads();
  if (tid == 0) out[0] = (tmp[0] + tmp[1]) * (1.f / 128.f);
}

// ---------------------------------------------------------------------------
// Workspace layout (bytes): same as R8 (~51.4 MB named; gatex tail overlaps
// the later-phase buffers deliberately — gatex is dead after the chunk loop)
// ---------------------------------------------------------------------------
extern "C" void kernel_launch(void* const* d_in, const int* in_sizes, int n_in,
                              void* d_out, int out_size, void* d_ws, size_t ws_size,
                              hipStream_t stream)
{
  const int* sentence = (const int*)d_in[0];
  const int* tags = (const int*)d_in[1];
  const float* embed = (const float*)d_in[2];
  const float* Wihf = (const float*)d_in[3];
  const float* Whhf = (const float*)d_in[4];
  const float* bihf = (const float*)d_in[5];
  const float* bhhf = (const float*)d_in[6];
  const float* Wihb = (const float*)d_in[7];
  const float* Whhb = (const float*)d_in[8];
  const float* bihb = (const float*)d_in[9];
  const float* bhhb = (const float*)d_in[10];
  const float* Wout = (const float*)d_in[11];
  const float* bout = (const float*)d_in[12];
  const float* trans = (const float*)d_in[13];
  const float* h0 = (const float*)d_in[14];
  const float* c0 = (const float*)d_in[15];
  float* out = (float*)d_out;

  char* ws = (char*)d_ws;
  uint* wihI = (uint*)(ws + 0);
  uint* whh = (uint*)(ws + 262144);
  uint* woutp = (uint*)(ws + 524288);
  float* biasI = (float*)(ws + 540672);
  float* numb = (float*)(ws + 544768);
  float* denb = (float*)(ws + 545280);
  float* statec = (float*)(ws + 545792);
  uint* hh = (uint*)(ws + 1048576);
  uint* gatex = (uint*)(ws + 34603008);
  float* feats = (float*)(ws + 34603008);
  uint* segP = (uint*)(ws + 42991616);
  float* segL = (float*)(ws + 51380224);

  hipLaunchKernelGGL(prep_kernel, dim3(532), dim3(256), 0, stream,
                     Wihf, Whhf, bihf, bhhf, Wihb, Whhb, bihb, bhhb, Wout,
                     wihI, whh, woutp, biasI);
  for (int c = 0; c < 4; ++c) {
    hipLaunchKernelGGL(gemmx_kernel, dim3(1024), dim3(256), 0, stream,
                       sentence, embed, wihI, biasI, gatex, c);
    hipLaunchKernelGGL(lstm_kernel, dim3(256), dim3(512), 0, stream,
                       gatex, whh, h0, c0, statec, hh, c);
  }
  hipLaunchKernelGGL(outproj_kernel, dim3(8192), dim3(256), 0, stream,
                     hh, woutp, bout, feats);
  hipLaunchKernelGGL(crf_num_kernel, dim3(128), dim3(64), 0, stream,
                     tags, feats, trans, numb);
  hipLaunchKernelGGL(crf_seg_kernel, dim3(4096), dim3(64), 0, stream,
                     feats, trans, segP, segL);
  hipLaunchKernelGGL(crf_comb_kernel, dim3(128), dim3(64), 0, stream,
                     feats, trans, segP, segL, denb);
  hipLaunchKernelGGL(final_kernel, dim3(1), dim3(128), 0, stream,
                     numb, denb, out);
}

// Round 5
// 594.516 us; speedup vs baseline: 1.1544x; 1.0012x over previous
//
#include <hip/hip_runtime.h>

typedef unsigned int uint;
typedef __fp16 half2_t __attribute__((ext_vector_type(2)));
typedef __fp16 half8_t __attribute__((ext_vector_type(8)));
typedef float floatx4 __attribute__((ext_vector_type(4)));

#define SEQ 512
#define BATCH 128
#define HID 128
#define NTAG 32
#define START_TAG 30
#define END_TAG 31

__device__ __forceinline__ float fdot2(uint a, uint b, float c) {
  return __builtin_amdgcn_fdot2(__builtin_bit_cast(half2_t, a),
                                __builtin_bit_cast(half2_t, b), c, false);
}
__device__ __forceinline__ uint packh2(float a, float b) {
  half2_t h = __builtin_amdgcn_cvt_pkrtz(a, b);
  return __builtin_bit_cast(uint, h);
}
__device__ __forceinline__ float frcp(float x) { return __builtin_amdgcn_rcpf(x); }
__device__ __forceinline__ float fsig(float x) { return frcp(1.f + __expf(-x)); }
__device__ __forceinline__ float ftanh(float x) { return 1.f - 2.f * frcp(1.f + __expf(2.f * x)); }
__device__ __forceinline__ float fexp2(float x) { return __builtin_amdgcn_exp2f(x); }
__device__ __forceinline__ float flog2(float x) { return __builtin_amdgcn_logf(x); }

// Quad butterfly sum via DPP quad_perm (VALU pipe, no LDS):
// 0xB1 = quad_perm[1,0,3,2] (xor 1), 0x4E = quad_perm[2,3,0,1] (xor 2).
__device__ __forceinline__ float quad_add(float x) {
  int a = __builtin_bit_cast(int, x);
  int b = __builtin_amdgcn_update_dpp(0, a, 0xB1, 0xF, 0xF, true);
  float y = x + __builtin_bit_cast(float, b);
  int c2 = __builtin_bit_cast(int, y);
  int d2 = __builtin_amdgcn_update_dpp(0, c2, 0x4E, 0xF, 0xF, true);
  return y + __builtin_bit_cast(float, d2);
}

// ---------------------------------------------------------------------------
// prep (unchanged from R8)
// ---------------------------------------------------------------------------
__global__ __launch_bounds__(256) void prep_kernel(
    const float* __restrict__ Wihf, const float* __restrict__ Whhf,
    const float* __restrict__ bihf, const float* __restrict__ bhhf,
    const float* __restrict__ Wihb, const float* __restrict__ Whhb,
    const float* __restrict__ bihb, const float* __restrict__ bhhb,
    const float* __restrict__ Wout,
    uint* __restrict__ wihI, uint* __restrict__ whh,
    uint* __restrict__ woutp, float* __restrict__ biasI)
{
  int idx = blockIdx.x * 256 + threadIdx.x;
  if (idx < 65536) {
    int d = idx >> 15, rem = idx & 32767;
    int n = rem >> 6, dw = rem & 63;
    int m = n >> 2, q = n & 3;
    int g = q * 128 + m;
    const float* W = d ? Wihb : Wihf;
    wihI[idx] = packh2(W[g * 128 + 2 * dw], W[g * 128 + 2 * dw + 1]);
  }
  int i2 = idx - 65536;
  if (i2 >= 0 && i2 < 65536) {
    int d = i2 >> 15, rem = i2 & 32767;
    int g = rem >> 6, dw = rem & 63;
    const float* W = d ? Whhb : Whhf;
    whh[i2] = packh2(W[g * 128 + 2 * dw], W[g * 128 + 2 * dw + 1]);
  }
  int i3 = idx - 131072;
  if (i3 >= 0 && i3 < 4096) {
    int k = i3 >> 7, dw = i3 & 127;
    float a, b2;
    if (dw < 64) { a = Wout[k * 256 + 2 * dw]; b2 = Wout[k * 256 + 2 * dw + 1]; }
    else { int j = dw - 64; a = Wout[k * 256 + 128 + 2 * j]; b2 = Wout[k * 256 + 128 + 2 * j + 1]; }
    woutp[i3] = packh2(a, b2);
  }
  int i4 = idx - 135168;
  if (i4 >= 0 && i4 < 1024) {
    int d = i4 >> 9, n = i4 & 511;
    int g = (n & 3) * 128 + (n >> 2);
    biasI[i4] = d ? (bihb[g] + bhhb[g]) : (bihf[g] + bhhf[g]);
  }
}

// ---------------------------------------------------------------------------
// gemmx (unchanged from R8)
// ---------------------------------------------------------------------------
__global__ __launch_bounds__(256, 2) void gemmx_kernel(
    const int* __restrict__ sentence, const float* __restrict__ embed,
    const uint* __restrict__ wihI, const float* __restrict__ biasI,
    uint* __restrict__ gatex, int chunk)
{
  int blk = blockIdx.x;
  int tl = blk & 127, nb = (blk >> 7) & 3, d = blk >> 9;
  int t = chunk * 128 + tl;
  int s = d ? (511 - t) : t;
  __shared__ int tok[128];
  int tid = threadIdx.x;
  if (tid < 128) tok[tid] = sentence[tid * SEQ + s];
  __syncthreads();

  int w = tid >> 6, lane = tid & 63;
  int q = lane >> 4, r = lane & 15;
  int wr = w >> 1, wc = w & 1;
  int r0 = wr * 64;
  int c0 = nb * 128 + wc * 64;

  floatx4 acc[4][4];
#pragma unroll
  for (int i = 0; i < 4; ++i)
#pragma unroll
    for (int j = 0; j < 4; ++j) acc[i][j] = (floatx4){0.f, 0.f, 0.f, 0.f};

  const float4* aptr[4];
#pragma unroll
  for (int i = 0; i < 4; ++i)
    aptr[i] = (const float4*)(embed + (size_t)tok[r0 + i * 16 + r] * HID) + q * 2;
  const uint4* bptr[4];
#pragma unroll
  for (int j = 0; j < 4; ++j)
    bptr[j] = (const uint4*)(wihI + ((size_t)d * 512 + c0 + j * 16 + r) * 64) + q;

#pragma unroll
  for (int kc = 0; kc < 4; ++kc) {
    half8_t af[4], bf[4];
#pragma unroll
    for (int i = 0; i < 4; ++i) {
      float4 x0 = aptr[i][kc * 8];
      float4 x1 = aptr[i][kc * 8 + 1];
      uint4 u;
      u.x = packh2(x0.x, x0.y); u.y = packh2(x0.z, x0.w);
      u.z = packh2(x1.x, x1.y); u.w = packh2(x1.z, x1.w);
      af[i] = __builtin_bit_cast(half8_t, u);
    }
#pragma unroll
    for (int j = 0; j < 4; ++j)
      bf[j] = __builtin_bit_cast(half8_t, bptr[j][kc * 4]);
#pragma unroll
    for (int i = 0; i < 4; ++i)
#pragma unroll
      for (int j = 0; j < 4; ++j)
        acc[i][j] = __builtin_amdgcn_mfma_f32_16x16x32_f16(af[i], bf[j], acc[i][j], 0, 0, 0);
  }

  __fp16* gat = ((__fp16*)gatex) + (size_t)d * 16384 * 512;
#pragma unroll
  for (int j = 0; j < 4; ++j) {
    int n = c0 + j * 16 + r;
    float bb = biasI[d * 512 + n];
#pragma unroll
    for (int i = 0; i < 4; ++i) {
      int rb = r0 + i * 16 + q * 4;
#pragma unroll
      for (int reg = 0; reg < 4; ++reg) {
        float v = acc[i][j][reg] + bb;
        gat[((size_t)(tl * 128 + rb + reg)) * 512 + n] = (__fp16)v;
      }
    }
  }
}

// ---------------------------------------------------------------------------
// LSTM recurrence — R14.
// R13 post-mortem: R8/R11/R13 all converge to ~1600 cyc/step despite
// different VALU/LDS mixes. Common factor: __syncthreads() per step, and
// hipcc emits `s_waitcnt vmcnt(0) lgkmcnt(0)` before the barrier (m97
// structural stall) -> every step DRAINS the 4-deep gatex prefetch and
// pays the full ~900cyc memory latency. Fix (m218-verified pattern):
// in-loop barrier = ds_write -> sched_barrier(0) -> asm lgkmcnt(0) ->
// sched_barrier(0) -> raw s_barrier builtin (no implicit vmcnt drain).
// gatex loads are thread-private; letting them fly across barriers is
// safe. Compiler still inserts counted vmcnt(N) before each gx use.
// Expected: dur 87 -> 30-42us, VALUBusy -> ~80%.
// ---------------------------------------------------------------------------
__global__ __attribute__((amdgpu_waves_per_eu(2, 2))) __launch_bounds__(512)
void lstm_kernel(
    const uint* __restrict__ gatex, const uint* __restrict__ whh,
    const float* __restrict__ h0, const float* __restrict__ c0,
    float* __restrict__ statec, uint* __restrict__ hh, int chunk)
{
  const int wg = blockIdx.x;
  const int d = wg >> 7, b = wg & 127;
  const int tid = threadIdx.x;
  const int kq = tid & 3, m = tid >> 2;

  __shared__ __align__(16) __fp16 hist[128][128];   // 32 KB

  // Weights: gate g row = g*128+m (64 uints); this thread's quarter = 4 uint4.
  const uint4* wh4 = (const uint4*)whh + (size_t)d * 8192;
  uint4 wreg[4][4];
#pragma unroll
  for (int g = 0; g < 4; ++g) {
    const uint4* row = wh4 + ((size_t)(g * 128 + m)) * 16 + kq * 4;
#pragma unroll
    for (int i = 0; i < 4; ++i) wreg[g][i] = row[i];
  }

  float c = (chunk == 0) ? c0[(size_t)(d * 128 + b) * 128 + m]
                         : statec[(size_t)(d * 128 + b) * 128 + m];

  if (tid < 64) {
    uint* h127 = (uint*)&hist[127][0];
    if (chunk == 0) {
      float2 hv = ((const float2*)(h0 + (size_t)(d * 128 + b) * 128))[tid];
      h127[tid] = packh2(hv.x, hv.y);
    } else {
      int sprev = d ? (511 - (chunk * 128 - 1)) : (chunk * 128 - 1);
      h127[tid] = hh[((size_t)(d * 512 + sprev) * 128 + b) * 64 + tid];
    }
  }
  // Gate-x (input contribution): halfs 4m..4m+3 = (i,f,g,o) for unit m.
  const uint* gx0 = gatex + (size_t)d * 4194304 + (size_t)b * 256 + 2 * m;

  // One LSTM step: consume gate-x gxc at timestep tl_.
  auto step = [&](int tl_, uint2 gxc) {
    float a0 = 0.f, a1 = 0.f, a2 = 0.f, a3 = 0.f;
    const uint4* z4 = (const uint4*)(&hist[(tl_ + 127) & 127][kq * 32]);
#pragma unroll
    for (int i = 0; i < 4; ++i) {
      uint4 z = z4[i];
      a0 = fdot2(z.x, wreg[0][i].x, a0);
      a0 = fdot2(z.y, wreg[0][i].y, a0);
      a0 = fdot2(z.z, wreg[0][i].z, a0);
      a0 = fdot2(z.w, wreg[0][i].w, a0);
      a1 = fdot2(z.x, wreg[1][i].x, a1);
      a1 = fdot2(z.y, wreg[1][i].y, a1);
      a1 = fdot2(z.z, wreg[1][i].z, a1);
      a1 = fdot2(z.w, wreg[1][i].w, a1);
      a2 = fdot2(z.x, wreg[2][i].x, a2);
      a2 = fdot2(z.y, wreg[2][i].y, a2);
      a2 = fdot2(z.z, wreg[2][i].z, a2);
      a2 = fdot2(z.w, wreg[2][i].w, a2);
      a3 = fdot2(z.x, wreg[3][i].x, a3);
      a3 = fdot2(z.y, wreg[3][i].y, a3);
      a3 = fdot2(z.z, wreg[3][i].z, a3);
      a3 = fdot2(z.w, wreg[3][i].w, a3);
    }
    // quad butterfly over k-quarters (DPP, VALU-only).
    a0 = quad_add(a0);
    a1 = quad_add(a1);
    a2 = quad_add(a2);
    a3 = quad_add(a3);

    half2_t g01 = __builtin_bit_cast(half2_t, gxc.x);
    half2_t g23 = __builtin_bit_cast(half2_t, gxc.y);
    a0 += (float)g01[0];
    a1 += (float)g01[1];
    a2 += (float)g23[0];
    a3 += (float)g23[1];

    float ig = fsig(a0);
    float fg = fsig(a1);
    float gg = ftanh(a2);
    float og = fsig(a3);
    c = fg * c + ig * gg;
    float hv = og * ftanh(c);

    if (kq == 0) hist[tl_][m] = (__fp16)hv;
    // Barrier WITHOUT vmcnt drain: lgkmcnt(0) covers the ds_write above;
    // prefetched gatex loads stay in flight across the barrier.
    __builtin_amdgcn_sched_barrier(0);
    asm volatile("s_waitcnt lgkmcnt(0)");
    __builtin_amdgcn_sched_barrier(0);
    __builtin_amdgcn_s_barrier();
  };

  // 4-deep gate-x prefetch ring (static indices; ~4-step HBM hiding window).
  uint2 g0 = *(const uint2*)(gx0);
  uint2 g1 = *(const uint2*)(gx0 + (size_t)1 * 32768);
  uint2 g2 = *(const uint2*)(gx0 + (size_t)2 * 32768);
  uint2 g3 = *(const uint2*)(gx0 + (size_t)3 * 32768);
  __syncthreads();

  for (int tl = 0; tl < 128; tl += 4) {
    int i0 = tl + 4 > 127 ? 127 : tl + 4;
    int i1 = tl + 5 > 127 ? 127 : tl + 5;
    int i2 = tl + 6 > 127 ? 127 : tl + 6;
    int i3 = tl + 7 > 127 ? 127 : tl + 7;
    uint2 n0 = *(const uint2*)(gx0 + (size_t)i0 * 32768);
    uint2 n1 = *(const uint2*)(gx0 + (size_t)i1 * 32768);
    uint2 n2 = *(const uint2*)(gx0 + (size_t)i2 * 32768);
    uint2 n3 = *(const uint2*)(gx0 + (size_t)i3 * 32768);
    step(tl + 0, g0);
    step(tl + 1, g1);
    step(tl + 2, g2);
    step(tl + 3, g3);
    g0 = n0; g1 = n1; g2 = n2; g3 = n3;
  }

  if (kq == 0) statec[(size_t)(d * 128 + b) * 128 + m] = c;

  int base = chunk * 128;
  for (int i = tid; i < 2048; i += 512) {
    int sl = i >> 4, q4 = i & 15;
    int s = d ? (511 - (base + sl)) : (base + sl);
    *(uint4*)(&hh[((size_t)(d * 512 + s) * 128 + b) * 64 + q4 * 4]) =
        *(const uint4*)((const uint*)&hist[sl][0] + q4 * 4);
  }
}

// ---------------------------------------------------------------------------
// Output projection (unchanged from R8)
// ---------------------------------------------------------------------------
__global__ __launch_bounds__(256) void outproj_kernel(
    const uint* __restrict__ hh, const uint* __restrict__ woutp,
    const float* __restrict__ bout, float* __restrict__ feats)
{
  __shared__ __align__(16) uint4 zrow[8][32];
  __shared__ __align__(16) uint4 wlds[32][32];
  int tid = threadIdx.x;
  for (int j = tid; j < 1024; j += 256) {
    int k = j >> 5, i = j & 31;
    wlds[i][k] = ((const uint4*)woutp)[j];
  }
  int rl = tid >> 5, q = tid & 31;
  int row = blockIdx.x * 8 + rl;
  int b = row >> 9, s = row & 511;
  const uint4* hf4 = (const uint4*)(hh + ((size_t)s * BATCH + b) * 64);
  const uint4* hb4 = (const uint4*)(hh + ((size_t)(SEQ + s) * BATCH + b) * 64);
  zrow[rl][q] = (q < 16) ? hf4[q] : hb4[q - 16];
  __syncthreads();
  int k = q;
  float acc = bout[k];
#pragma unroll
  for (int i = 0; i < 32; ++i) {
    uint4 z = zrow[rl][i];
    uint4 wv = wlds[i][k];
    acc = fdot2(z.x, wv.x, acc);
    acc = fdot2(z.y, wv.y, acc);
    acc = fdot2(z.z, wv.z, acc);
    acc = fdot2(z.w, wv.w, acc);
  }
  feats[(size_t)row * 32 + k] = acc;
}

// ---------------------------------------------------------------------------
// CRF numerator (unchanged)
// ---------------------------------------------------------------------------
__global__ __launch_bounds__(64) void crf_num_kernel(
    const int* __restrict__ tags, const float* __restrict__ feats,
    const float* __restrict__ trans, float* __restrict__ num)
{
  int b = blockIdx.x, l = threadIdx.x;
  const int* tb = tags + b * SEQ;
  float acc = 0.f;
  for (int s = l; s < SEQ; s += 64) {
    int tg = tb[s];
    int pv = (s == 0) ? START_TAG : tb[s - 1];
    acc += trans[pv * NTAG + tg] + feats[((size_t)b * SEQ + s) * NTAG + tg];
  }
#pragma unroll
  for (int msk = 1; msk < 64; msk <<= 1) acc += __shfl_xor(acc, msk);
  if (l == 0) num[b] = acc + trans[tb[SEQ - 1] * NTAG + END_TAG];
}

// ---------------------------------------------------------------------------
// CRF stage A (unchanged from R8)
// ---------------------------------------------------------------------------
__global__ __launch_bounds__(64) void crf_seg_kernel(
    const float* __restrict__ feats, const float* __restrict__ trans,
    uint* __restrict__ segP, float* __restrict__ segL)
{
  const float L2E = 1.4426950408889634f;
  int blk = blockIdx.x;
  int b = blk >> 5, j = blk & 31;
  int tstart = 1 + 16 * j;
  int nsteps = (j == 31) ? 15 : 16;
  int lane = threadIdx.x;
  int c = lane & 15, q = lane >> 4;

  half8_t afr[2];
#pragma unroll
  for (int rt = 0; rt < 2; ++rt) {
    const float* trow = trans + (rt * 16 + c) * 32 + q * 8;
    float e[8];
#pragma unroll
    for (int i = 0; i < 8; ++i) e[i] = fexp2(trow[i] * L2E);
    uint4 u;
    u.x = packh2(e[0], e[1]); u.y = packh2(e[2], e[3]);
    u.z = packh2(e[4], e[5]); u.w = packh2(e[6], e[7]);
    afr[rt] = __builtin_bit_cast(half8_t, u);
  }
  half8_t bfr[2];
#pragma unroll
  for (int ct = 0; ct < 2; ++ct) {
    uint4 u;
    uint vals[8];
#pragma unroll
    for (int i = 0; i < 8; ++i)
      vals[i] = ((q * 8 + i) == (ct * 16 + c)) ? 0x3C00u : 0u;
    u.x = vals[0] | (vals[1] << 16);
    u.y = vals[2] | (vals[3] << 16);
    u.z = vals[4] | (vals[5] << 16);
    u.w = vals[6] | (vals[7] << 16);
    bfr[ct] = __builtin_bit_cast(half8_t, u);
  }

  __shared__ __fp16 P16[32 * 36];

  const float* fb = feats + ((size_t)b * SEQ + tstart) * NTAG;
  float Lacc = 0.f;
  float4 pre0 = *(const float4*)(fb + q * 4);
  float4 pre1 = *(const float4*)(fb + 16 + q * 4);

  for (int s = 0; s < nsteps; ++s) {
    float4 f0 = pre0, f1 = pre1;
    if (s + 1 < nsteps) {
      pre0 = *(const float4*)(fb + (s + 1) * 32 + q * 4);
      pre1 = *(const float4*)(fb + (s + 1) * 32 + 16 + q * 4);
    }
    floatx4 z4 = (floatx4){0.f, 0.f, 0.f, 0.f};
    floatx4 c00 = __builtin_amdgcn_mfma_f32_16x16x32_f16(afr[0], bfr[0], z4, 0, 0, 0);
    floatx4 c01 = __builtin_amdgcn_mfma_f32_16x16x32_f16(afr[0], bfr[1], z4, 0, 0, 0);
    floatx4 c10 = __builtin_amdgcn_mfma_f32_16x16x32_f16(afr[1], bfr[0], z4, 0, 0, 0);
    floatx4 c11 = __builtin_amdgcn_mfma_f32_16x16x32_f16(afr[1], bfr[1], z4, 0, 0, 0);
    float pf0[4], pf1[4];
    pf0[0] = fexp2(f0.x * L2E); pf0[1] = fexp2(f0.y * L2E);
    pf0[2] = fexp2(f0.z * L2E); pf0[3] = fexp2(f0.w * L2E);
    pf1[0] = fexp2(f1.x * L2E); pf1[1] = fexp2(f1.y * L2E);
    pf1[2] = fexp2(f1.z * L2E); pf1[3] = fexp2(f1.w * L2E);
    float v00[4], v01[4], v10[4], v11[4];
#pragma unroll
    for (int rg = 0; rg < 4; ++rg) {
      v00[rg] = c00[rg] * pf0[rg];
      v01[rg] = c01[rg] * pf0[rg];
      v10[rg] = c10[rg] * pf1[rg];
      v11[rg] = c11[rg] * pf1[rg];
    }
    float mx = 0.f;
#pragma unroll
    for (int rg = 0; rg < 4; ++rg)
      mx = fmaxf(mx, fmaxf(fmaxf(v00[rg], v01[rg]), fmaxf(v10[rg], v11[rg])));
    uint ub = (uint)__builtin_amdgcn_readfirstlane((int)__builtin_bit_cast(uint, mx));
    int e = (int)((ub >> 23) & 255u);
    Lacc += (float)(e - 127);
    float sc = __builtin_bit_cast(float, (uint)((254 - e) << 23));

    __syncthreads();
    {
      uint2 wv2;
      wv2.x = packh2(v00[0] * sc, v00[1] * sc);
      wv2.y = packh2(v00[2] * sc, v00[3] * sc);
      *(uint2*)(&P16[c * 36 + q * 4]) = wv2;
      wv2.x = packh2(v10[0] * sc, v10[1] * sc);
      wv2.y = packh2(v10[2] * sc, v10[3] * sc);
      *(uint2*)(&P16[c * 36 + 16 + q * 4]) = wv2;
      wv2.x = packh2(v01[0] * sc, v01[1] * sc);
      wv2.y = packh2(v01[2] * sc, v01[3] * sc);
      *(uint2*)(&P16[(16 + c) * 36 + q * 4]) = wv2;
      wv2.x = packh2(v11[0] * sc, v11[1] * sc);
      wv2.y = packh2(v11[2] * sc, v11[3] * sc);
      *(uint2*)(&P16[(16 + c) * 36 + 16 + q * 4]) = wv2;
    }
    __syncthreads();
    {
      uint2 lo0 = *(const uint2*)(&P16[c * 36 + q * 8]);
      uint2 hi0 = *(const uint2*)(&P16[c * 36 + q * 8 + 4]);
      uint4 u0; u0.x = lo0.x; u0.y = lo0.y; u0.z = hi0.x; u0.w = hi0.y;
      bfr[0] = __builtin_bit_cast(half8_t, u0);
      uint2 lo1 = *(const uint2*)(&P16[(16 + c) * 36 + q * 8]);
      uint2 hi1 = *(const uint2*)(&P16[(16 + c) * 36 + q * 8 + 4]);
      uint4 u1; u1.x = lo1.x; u1.y = lo1.y; u1.z = hi1.x; u1.w = hi1.y;
      bfr[1] = __builtin_bit_cast(half8_t, u1);
    }
  }
  __syncthreads();
  uint* gp = segP + (size_t)blk * 512;
  if (lane < 32) {
    int i = lane;
#pragma unroll
    for (int tp = 0; tp < 16; ++tp) {
      uint lo = (uint)__builtin_bit_cast(unsigned short, P16[(2 * tp) * 36 + i]);
      uint hi = (uint)__builtin_bit_cast(unsigned short, P16[(2 * tp + 1) * 36 + i]);
      gp[i * 16 + tp] = lo | (hi << 16);
    }
  }
  if (lane == 0) segL[blk] = Lacc;
}

// ---------------------------------------------------------------------------
// CRF stage B (unchanged from R8)
// ---------------------------------------------------------------------------
__global__ __launch_bounds__(64) void crf_comb_kernel(
    const float* __restrict__ feats, const float* __restrict__ trans,
    const uint* __restrict__ segP, const float* __restrict__ segL,
    float* __restrict__ den)
{
  const float L2E = 1.4426950408889634f, LN2 = 0.6931471805599453f;
  int b = blockIdx.x, l = threadIdx.x;
  int i = l & 31, hp = l >> 5;
  const float* fb = feats + (size_t)b * SEQ * NTAG;

  float sT = 0.f;
  for (int p = 0; p < 32; ++p) sT += fexp2(trans[i * 32 + p] * L2E);
  float v = (1.f + sT) * fexp2(fb[i] * L2E);
  float L = -10000.f * L2E;

  float vo = __shfl_xor(v, 1);
  uint pv = (i & 1) ? packh2(vo, v) : packh2(v, vo);

  const uint* gp0 = segP + (size_t)b * 32 * 512 + i * 16 + hp * 8;
  uint4 ra = *(const uint4*)(gp0);
  uint4 rb = *(const uint4*)(gp0 + 4);

  for (int seg = 0; seg < 32; ++seg) {
    uint4 ca = ra, cb = rb;
    if (seg + 1 < 32) {
      ra = *(const uint4*)(gp0 + (seg + 1) * 512);
      rb = *(const uint4*)(gp0 + (seg + 1) * 512 + 4);
    }
    float g0 = __shfl(__builtin_bit_cast(float, pv), hp * 16 + 0);
    float g1 = __shfl(__builtin_bit_cast(float, pv), hp * 16 + 2);
    float g2 = __shfl(__builtin_bit_cast(float, pv), hp * 16 + 4);
    float g3 = __shfl(__builtin_bit_cast(float, pv), hp * 16 + 6);
    float g4 = __shfl(__builtin_bit_cast(float, pv), hp * 16 + 8);
    float g5 = __shfl(__builtin_bit_cast(float, pv), hp * 16 + 10);
    float g6 = __shfl(__builtin_bit_cast(float, pv), hp * 16 + 12);
    float g7 = __shfl(__builtin_bit_cast(float, pv), hp * 16 + 14);
    float acc = 0.f;
    acc = fdot2(__builtin_bit_cast(uint, g0), ca.x, acc);
    acc = fdot2(__builtin_bit_cast(uint, g1), ca.y, acc);
    acc = fdot2(__builtin_bit_cast(uint, g2), ca.z, acc);
    acc = fdot2(__builtin_bit_cast(uint, g3), ca.w, acc);
    acc = fdot2(__builtin_bit_cast(uint, g4), cb.x, acc);
    acc = fdot2(__builtin_bit_cast(uint, g5), cb.y, acc);
    acc = fdot2(__builtin_bit_cast(uint, g6), cb.z, acc);
    acc = fdot2(__builtin_bit_cast(uint, g7), cb.w, acc);
    float sm = acc + __shfl_xor(acc, 32);
    uint ub = (uint)__builtin_amdgcn_readfirstlane((int)__builtin_bit_cast(uint, sm));
    int e = (int)((ub >> 23) & 255u);
    L += (float)(e - 127) + segL[b * 32 + seg];
    float sc = __builtin_bit_cast(float, (uint)((254 - e) << 23));
    v = sm * sc;
    float vo2 = __shfl_xor(v, 1);
    pv = (i & 1) ? packh2(vo2, v) : packh2(v, vo2);
  }
  float wv = v * fexp2(trans[i * 32 + END_TAG] * L2E);
#pragma unroll
  for (int msk = 1; msk <= 16; msk <<= 1) wv += __shfl_xor(wv, msk);
  if (l == 0) den[b] = (L + flog2(wv)) * LN2;
}

__global__ __launch_bounds__(128) void final_kernel(
    const float* __restrict__ num, const float* __restrict__ den,
    float* __restrict__ out)
{
  int tid = threadIdx.x;
  float v = num[tid] - den[tid];
#pragma unroll
  for (int msk = 1; msk < 64; msk <<= 1) v += __shfl_xor(v, msk);
  __shared__ float tmp[2];
  if ((tid & 63) == 0) tmp[tid >> 6] = v;
  __syncthreads();
  if (tid == 0) out[0] = (tmp[0] + tmp[1]) * (1.f / 128.f);
}

// ---------------------------------------------------------------------------
// Workspace layout (bytes): same as R8 (~51.4 MB named; gatex tail overlaps
// the later-phase buffers deliberately — gatex is dead after the chunk loop)
// ---------------------------------------------------------------------------
extern "C" void kernel_launch(void* const* d_in, const int* in_sizes, int n_in,
                              void* d_out, int out_size, void* d_ws, size_t ws_size,
                              hipStream_t stream)
{
  const int* sentence = (const int*)d_in[0];
  const int* tags = (const int*)d_in[1];
  const float* embed = (const float*)d_in[2];
  const float* Wihf = (const float*)d_in[3];
  const float* Whhf = (const float*)d_in[4];
  const float* bihf = (const float*)d_in[5];
  const float* bhhf = (const float*)d_in[6];
  const float* Wihb = (const float*)d_in[7];
  const float* Whhb = (const float*)d_in[8];
  const float* bihb = (const float*)d_in[9];
  const float* bhhb = (const float*)d_in[10];
  const float* Wout = (const float*)d_in[11];
  const float* bout = (const float*)d_in[12];
  const float* trans = (const float*)d_in[13];
  const float* h0 = (const float*)d_in[14];
  const float* c0 = (const float*)d_in[15];
  float* out = (float*)d_out;

  char* ws = (char*)d_ws;
  uint* wihI = (uint*)(ws + 0);
  uint* whh = (uint*)(ws + 262144);
  uint* woutp = (uint*)(ws + 524288);
  float* biasI = (float*)(ws + 540672);
  float* numb = (float*)(ws + 544768);
  float* denb = (float*)(ws + 545280);
  float* statec = (float*)(ws + 545792);
  uint* hh = (uint*)(ws + 1048576);
  uint* gatex = (uint*)(ws + 34603008);
  float* feats = (float*)(ws + 34603008);
  uint* segP = (uint*)(ws + 42991616);
  float* segL = (float*)(ws + 51380224);

  hipLaunchKernelGGL(prep_kernel, dim3(532), dim3(256), 0, stream,
                     Wihf, Whhf, bihf, bhhf, Wihb, Whhb, bihb, bhhb, Wout,
                     wihI, whh, woutp, biasI);
  for (int c = 0; c < 4; ++c) {
    hipLaunchKernelGGL(gemmx_kernel, dim3(1024), dim3(256), 0, stream,
                       sentence, embed, wihI, biasI, gatex, c);
    hipLaunchKernelGGL(lstm_kernel, dim3(256), dim3(512), 0, stream,
                       gatex, whh, h0, c0, statec, hh, c);
  }
  hipLaunchKernelGGL(outproj_kernel, dim3(8192), dim3(256), 0, stream,
                     hh, woutp, bout, feats);
  hipLaunchKernelGGL(crf_num_kernel, dim3(128), dim3(64), 0, stream,
                     tags, feats, trans, numb);
  hipLaunchKernelGGL(crf_seg_kernel, dim3(4096), dim3(64), 0, stream,
                     feats, trans, segP, segL);
  hipLaunchKernelGGL(crf_comb_kernel, dim3(128), dim3(64), 0, stream,
                     feats, trans, segP, segL, denb);
  hipLaunchKernelGGL(final_kernel, dim3(1), dim3(128), 0, stream,
                     numb, denb, out);
}

// Round 6
// 563.884 us; speedup vs baseline: 1.2172x; 1.0543x over previous
//
#include <hip/hip_runtime.h>

typedef unsigned int uint;
typedef unsigned short ushort;
typedef __fp16 half2_t __attribute__((ext_vector_type(2)));
typedef __fp16 half8_t __attribute__((ext_vector_type(8)));
typedef float floatx4 __attribute__((ext_vector_type(4)));

#define SEQ 512
#define BATCH 128
#define HID 128
#define NTAG 32
#define START_TAG 30
#define END_TAG 31

__device__ __forceinline__ float fdot2(uint a, uint b, float c) {
  return __builtin_amdgcn_fdot2(__builtin_bit_cast(half2_t, a),
                                __builtin_bit_cast(half2_t, b), c, false);
}
__device__ __forceinline__ uint packh2(float a, float b) {
  half2_t h = __builtin_amdgcn_cvt_pkrtz(a, b);
  return __builtin_bit_cast(uint, h);
}
__device__ __forceinline__ float frcp(float x) { return __builtin_amdgcn_rcpf(x); }
__device__ __forceinline__ float fsig(float x) { return frcp(1.f + __expf(-x)); }
__device__ __forceinline__ float ftanh(float x) { return 1.f - 2.f * frcp(1.f + __expf(2.f * x)); }
__device__ __forceinline__ float fexp2(float x) { return __builtin_amdgcn_exp2f(x); }
__device__ __forceinline__ float flog2(float x) { return __builtin_amdgcn_logf(x); }

// Quad butterfly sum via DPP quad_perm (VALU pipe, no LDS):
// 0xB1 = quad_perm[1,0,3,2] (xor 1), 0x4E = quad_perm[2,3,0,1] (xor 2).
__device__ __forceinline__ float quad_add(float x) {
  int a = __builtin_bit_cast(int, x);
  int b = __builtin_amdgcn_update_dpp(0, a, 0xB1, 0xF, 0xF, true);
  float y = x + __builtin_bit_cast(float, b);
  int c2 = __builtin_bit_cast(int, y);
  int d2 = __builtin_amdgcn_update_dpp(0, c2, 0x4E, 0xF, 0xF, true);
  return y + __builtin_bit_cast(float, d2);
}
// Quad broadcast of lane L (CTRL = 0x00/0x55/0xAA/0xFF for L=0/1/2/3).
template <int CTRL>
__device__ __forceinline__ float quad_bcast(float x) {
  int a = __builtin_bit_cast(int, x);
  int b = __builtin_amdgcn_update_dpp(0, a, CTRL, 0xF, 0xF, true);
  return __builtin_bit_cast(float, b);
}

// ---------------------------------------------------------------------------
// prep (unchanged from R8)
// ---------------------------------------------------------------------------
__global__ __launch_bounds__(256) void prep_kernel(
    const float* __restrict__ Wihf, const float* __restrict__ Whhf,
    const float* __restrict__ bihf, const float* __restrict__ bhhf,
    const float* __restrict__ Wihb, const float* __restrict__ Whhb,
    const float* __restrict__ bihb, const float* __restrict__ bhhb,
    const float* __restrict__ Wout,
    uint* __restrict__ wihI, uint* __restrict__ whh,
    uint* __restrict__ woutp, float* __restrict__ biasI)
{
  int idx = blockIdx.x * 256 + threadIdx.x;
  if (idx < 65536) {
    int d = idx >> 15, rem = idx & 32767;
    int n = rem >> 6, dw = rem & 63;
    int m = n >> 2, q = n & 3;
    int g = q * 128 + m;
    const float* W = d ? Wihb : Wihf;
    wihI[idx] = packh2(W[g * 128 + 2 * dw], W[g * 128 + 2 * dw + 1]);
  }
  int i2 = idx - 65536;
  if (i2 >= 0 && i2 < 65536) {
    int d = i2 >> 15, rem = i2 & 32767;
    int g = rem >> 6, dw = rem & 63;
    const float* W = d ? Whhb : Whhf;
    whh[i2] = packh2(W[g * 128 + 2 * dw], W[g * 128 + 2 * dw + 1]);
  }
  int i3 = idx - 131072;
  if (i3 >= 0 && i3 < 4096) {
    int k = i3 >> 7, dw = i3 & 127;
    float a, b2;
    if (dw < 64) { a = Wout[k * 256 + 2 * dw]; b2 = Wout[k * 256 + 2 * dw + 1]; }
    else { int j = dw - 64; a = Wout[k * 256 + 128 + 2 * j]; b2 = Wout[k * 256 + 128 + 2 * j + 1]; }
    woutp[i3] = packh2(a, b2);
  }
  int i4 = idx - 135168;
  if (i4 >= 0 && i4 < 1024) {
    int d = i4 >> 9, n = i4 & 511;
    int g = (n & 3) * 128 + (n >> 2);
    biasI[i4] = d ? (bihb[g] + bhhb[g]) : (bihf[g] + bhhf[g]);
  }
}

// ---------------------------------------------------------------------------
// gemmx (unchanged from R8)
// ---------------------------------------------------------------------------
__global__ __launch_bounds__(256, 2) void gemmx_kernel(
    const int* __restrict__ sentence, const float* __restrict__ embed,
    const uint* __restrict__ wihI, const float* __restrict__ biasI,
    uint* __restrict__ gatex, int chunk)
{
  int blk = blockIdx.x;
  int tl = blk & 127, nb = (blk >> 7) & 3, d = blk >> 9;
  int t = chunk * 128 + tl;
  int s = d ? (511 - t) : t;
  __shared__ int tok[128];
  int tid = threadIdx.x;
  if (tid < 128) tok[tid] = sentence[tid * SEQ + s];
  __syncthreads();

  int w = tid >> 6, lane = tid & 63;
  int q = lane >> 4, r = lane & 15;
  int wr = w >> 1, wc = w & 1;
  int r0 = wr * 64;
  int c0 = nb * 128 + wc * 64;

  floatx4 acc[4][4];
#pragma unroll
  for (int i = 0; i < 4; ++i)
#pragma unroll
    for (int j = 0; j < 4; ++j) acc[i][j] = (floatx4){0.f, 0.f, 0.f, 0.f};

  const float4* aptr[4];
#pragma unroll
  for (int i = 0; i < 4; ++i)
    aptr[i] = (const float4*)(embed + (size_t)tok[r0 + i * 16 + r] * HID) + q * 2;
  const uint4* bptr[4];
#pragma unroll
  for (int j = 0; j < 4; ++j)
    bptr[j] = (const uint4*)(wihI + ((size_t)d * 512 + c0 + j * 16 + r) * 64) + q;

#pragma unroll
  for (int kc = 0; kc < 4; ++kc) {
    half8_t af[4], bf[4];
#pragma unroll
    for (int i = 0; i < 4; ++i) {
      float4 x0 = aptr[i][kc * 8];
      float4 x1 = aptr[i][kc * 8 + 1];
      uint4 u;
      u.x = packh2(x0.x, x0.y); u.y = packh2(x0.z, x0.w);
      u.z = packh2(x1.x, x1.y); u.w = packh2(x1.z, x1.w);
      af[i] = __builtin_bit_cast(half8_t, u);
    }
#pragma unroll
    for (int j = 0; j < 4; ++j)
      bf[j] = __builtin_bit_cast(half8_t, bptr[j][kc * 4]);
#pragma unroll
    for (int i = 0; i < 4; ++i)
#pragma unroll
      for (int j = 0; j < 4; ++j)
        acc[i][j] = __builtin_amdgcn_mfma_f32_16x16x32_f16(af[i], bf[j], acc[i][j], 0, 0, 0);
  }

  __fp16* gat = ((__fp16*)gatex) + (size_t)d * 16384 * 512;
#pragma unroll
  for (int j = 0; j < 4; ++j) {
    int n = c0 + j * 16 + r;
    float bb = biasI[d * 512 + n];
#pragma unroll
    for (int i = 0; i < 4; ++i) {
      int rb = r0 + i * 16 + q * 4;
#pragma unroll
      for (int reg = 0; reg < 4; ++reg) {
        float v = acc[i][j][reg] + bb;
        gat[((size_t)(tl * 128 + rb + reg)) * 512 + n] = (__fp16)v;
      }
    }
  }
}

// ---------------------------------------------------------------------------
// LSTM recurrence — R15.
// R14 post-mortem: raw-barrier (no vmcnt drain) = null -> memory latency is
// NOT the binder. Invariant: R8/R11/R13/R14 all ~1600 cyc/step; 1 vs 2
// waves/SIMD identical -> per-SIMD ISSUE bound (~1000 cyc, VALUBusy 62%).
// Biggest issue block: gate transcendentals computed 4x REDUNDANTLY (all
// kq lanes compute all of i,f,g,o after the butterfly broadcasts totals).
// R15: distribute nonlinearities across the quad:
//  * lane kq computes only gate kq: uniform path e=exp2(x*sl), r=rcp(1+e),
//    out=A*r+B with lane-const sl/A/B (sig for kq 0,1,3; tanh for kq 2).
//  * 4 DPP quad-broadcasts fan (i,f,g,o) back to all lanes; all lanes do
//    the cheap c-update + tanh(c). Transcendentals/thread: 10 -> 4.
//  * gatex load shrinks to own-gate ushort (kills unpack+select).
//  * gate-dot chains split into 2 partials (dep depth 16 -> 8).
// Expected: dur 86.5 -> 50-60us. Failure: >=75us -> serial-chain-bound.
// ---------------------------------------------------------------------------
__global__ __attribute__((amdgpu_waves_per_eu(2, 2))) __launch_bounds__(512)
void lstm_kernel(
    const uint* __restrict__ gatex, const uint* __restrict__ whh,
    const float* __restrict__ h0, const float* __restrict__ c0,
    float* __restrict__ statec, uint* __restrict__ hh, int chunk)
{
  const float L2E = 1.4426950408889634f;
  const int wg = blockIdx.x;
  const int d = wg >> 7, b = wg & 127;
  const int tid = threadIdx.x;
  const int kq = tid & 3, m = tid >> 2;

  __shared__ __align__(16) __fp16 hist[128][128];   // 32 KB

  // Lane-constant nonlinearity params: kq==2 -> tanh, else sigmoid.
  const bool isg = (kq == 2);
  const float sl = isg ? (2.f * L2E) : (-L2E);
  const float Ac = isg ? -2.f : 1.f;
  const float Bc = isg ? 1.f : 0.f;

  // Weights: gate g row = g*128+m (64 uints); this thread's quarter = 4 uint4.
  const uint4* wh4 = (const uint4*)whh + (size_t)d * 8192;
  uint4 wreg[4][4];
#pragma unroll
  for (int g = 0; g < 4; ++g) {
    const uint4* row = wh4 + ((size_t)(g * 128 + m)) * 16 + kq * 4;
#pragma unroll
    for (int i = 0; i < 4; ++i) wreg[g][i] = row[i];
  }

  float c = (chunk == 0) ? c0[(size_t)(d * 128 + b) * 128 + m]
                         : statec[(size_t)(d * 128 + b) * 128 + m];

  if (tid < 64) {
    uint* h127 = (uint*)&hist[127][0];
    if (chunk == 0) {
      float2 hv = ((const float2*)(h0 + (size_t)(d * 128 + b) * 128))[tid];
      h127[tid] = packh2(hv.x, hv.y);
    } else {
      int sprev = d ? (511 - (chunk * 128 - 1)) : (chunk * 128 - 1);
      h127[tid] = hh[((size_t)(d * 512 + sprev) * 128 + b) * 64 + tid];
    }
  }
  // Gate-x: this thread's own gate only (ushort at half index 4m+kq).
  const ushort* gxp = (const ushort*)gatex + (size_t)d * 8388608 +
                      (size_t)b * 512 + 4 * m + kq;

  // One LSTM step: consume own-gate gate-x value gxh at timestep tl_.
  auto step = [&](int tl_, ushort gxh) {
    float a0 = 0.f, a1 = 0.f, a2 = 0.f, a3 = 0.f;
    float b0 = 0.f, b1 = 0.f, b2 = 0.f, b3 = 0.f;
    const uint4* z4 = (const uint4*)(&hist[(tl_ + 127) & 127][kq * 32]);
#pragma unroll
    for (int i = 0; i < 2; ++i) {
      uint4 z = z4[i];
      a0 = fdot2(z.x, wreg[0][i].x, a0);
      a0 = fdot2(z.y, wreg[0][i].y, a0);
      a0 = fdot2(z.z, wreg[0][i].z, a0);
      a0 = fdot2(z.w, wreg[0][i].w, a0);
      a1 = fdot2(z.x, wreg[1][i].x, a1);
      a1 = fdot2(z.y, wreg[1][i].y, a1);
      a1 = fdot2(z.z, wreg[1][i].z, a1);
      a1 = fdot2(z.w, wreg[1][i].w, a1);
      a2 = fdot2(z.x, wreg[2][i].x, a2);
      a2 = fdot2(z.y, wreg[2][i].y, a2);
      a2 = fdot2(z.z, wreg[2][i].z, a2);
      a2 = fdot2(z.w, wreg[2][i].w, a2);
      a3 = fdot2(z.x, wreg[3][i].x, a3);
      a3 = fdot2(z.y, wreg[3][i].y, a3);
      a3 = fdot2(z.z, wreg[3][i].z, a3);
      a3 = fdot2(z.w, wreg[3][i].w, a3);
    }
#pragma unroll
    for (int i = 2; i < 4; ++i) {
      uint4 z = z4[i];
      b0 = fdot2(z.x, wreg[0][i].x, b0);
      b0 = fdot2(z.y, wreg[0][i].y, b0);
      b0 = fdot2(z.z, wreg[0][i].z, b0);
      b0 = fdot2(z.w, wreg[0][i].w, b0);
      b1 = fdot2(z.x, wreg[1][i].x, b1);
      b1 = fdot2(z.y, wreg[1][i].y, b1);
      b1 = fdot2(z.z, wreg[1][i].z, b1);
      b1 = fdot2(z.w, wreg[1][i].w, b1);
      b2 = fdot2(z.x, wreg[2][i].x, b2);
      b2 = fdot2(z.y, wreg[2][i].y, b2);
      b2 = fdot2(z.z, wreg[2][i].z, b2);
      b2 = fdot2(z.w, wreg[2][i].w, b2);
      b3 = fdot2(z.x, wreg[3][i].x, b3);
      b3 = fdot2(z.y, wreg[3][i].y, b3);
      b3 = fdot2(z.z, wreg[3][i].z, b3);
      b3 = fdot2(z.w, wreg[3][i].w, b3);
    }
    a0 += b0; a1 += b1; a2 += b2; a3 += b3;
    // quad butterfly over k-quarters (DPP, VALU-only): all lanes get totals.
    a0 = quad_add(a0);
    a1 = quad_add(a1);
    a2 = quad_add(a2);
    a3 = quad_add(a3);
    // Select own gate total; add own gate-x; apply own nonlinearity.
    float s01 = (kq & 1) ? a1 : a0;
    float s23 = (kq & 1) ? a3 : a2;
    float own = (kq & 2) ? s23 : s01;
    own += (float)__builtin_bit_cast(__fp16, gxh);
    float e = fexp2(own * sl);
    float r = frcp(1.f + e);
    float out = Ac * r + Bc;   // sig (kq 0,1,3) or tanh (kq 2)
    // Fan the 4 gate values back to all quad lanes.
    float ig = quad_bcast<0x00>(out);
    float fg = quad_bcast<0x55>(out);
    float gg = quad_bcast<0xAA>(out);
    float og = quad_bcast<0xFF>(out);
    c = fg * c + ig * gg;
    float e2 = fexp2(c * (2.f * L2E));
    float r2 = frcp(1.f + e2);
    float th = 1.f - 2.f * r2;
    float hv = og * th;

    if (kq == 0) hist[tl_][m] = (__fp16)hv;
    // Barrier WITHOUT vmcnt drain: lgkmcnt(0) covers the ds_write above;
    // prefetched gatex loads stay in flight across the barrier.
    __builtin_amdgcn_sched_barrier(0);
    asm volatile("s_waitcnt lgkmcnt(0)");
    __builtin_amdgcn_sched_barrier(0);
    __builtin_amdgcn_s_barrier();
  };

  // 4-deep gate-x prefetch ring (static indices).
  ushort g0 = gxp[0];
  ushort g1 = gxp[(size_t)1 * 65536];
  ushort g2 = gxp[(size_t)2 * 65536];
  ushort g3 = gxp[(size_t)3 * 65536];
  __syncthreads();

  for (int tl = 0; tl < 128; tl += 4) {
    int i0 = tl + 4 > 127 ? 127 : tl + 4;
    int i1 = tl + 5 > 127 ? 127 : tl + 5;
    int i2 = tl + 6 > 127 ? 127 : tl + 6;
    int i3 = tl + 7 > 127 ? 127 : tl + 7;
    ushort n0 = gxp[(size_t)i0 * 65536];
    ushort n1 = gxp[(size_t)i1 * 65536];
    ushort n2 = gxp[(size_t)i2 * 65536];
    ushort n3 = gxp[(size_t)i3 * 65536];
    step(tl + 0, g0);
    step(tl + 1, g1);
    step(tl + 2, g2);
    step(tl + 3, g3);
    g0 = n0; g1 = n1; g2 = n2; g3 = n3;
  }

  if (kq == 0) statec[(size_t)(d * 128 + b) * 128 + m] = c;

  int base = chunk * 128;
  for (int i = tid; i < 2048; i += 512) {
    int sl2 = i >> 4, q4 = i & 15;
    int s = d ? (511 - (base + sl2)) : (base + sl2);
    *(uint4*)(&hh[((size_t)(d * 512 + s) * 128 + b) * 64 + q4 * 4]) =
        *(const uint4*)((const uint*)&hist[sl2][0] + q4 * 4);
  }
}

// ---------------------------------------------------------------------------
// Output projection (unchanged from R8)
// ---------------------------------------------------------------------------
__global__ __launch_bounds__(256) void outproj_kernel(
    const uint* __restrict__ hh, const uint* __restrict__ woutp,
    const float* __restrict__ bout, float* __restrict__ feats)
{
  __shared__ __align__(16) uint4 zrow[8][32];
  __shared__ __align__(16) uint4 wlds[32][32];
  int tid = threadIdx.x;
  for (int j = tid; j < 1024; j += 256) {
    int k = j >> 5, i = j & 31;
    wlds[i][k] = ((const uint4*)woutp)[j];
  }
  int rl = tid >> 5, q = tid & 31;
  int row = blockIdx.x * 8 + rl;
  int b = row >> 9, s = row & 511;
  const uint4* hf4 = (const uint4*)(hh + ((size_t)s * BATCH + b) * 64);
  const uint4* hb4 = (const uint4*)(hh + ((size_t)(SEQ + s) * BATCH + b) * 64);
  zrow[rl][q] = (q < 16) ? hf4[q] : hb4[q - 16];
  __syncthreads();
  int k = q;
  float acc = bout[k];
#pragma unroll
  for (int i = 0; i < 32; ++i) {
    uint4 z = zrow[rl][i];
    uint4 wv = wlds[i][k];
    acc = fdot2(z.x, wv.x, acc);
    acc = fdot2(z.y, wv.y, acc);
    acc = fdot2(z.z, wv.z, acc);
    acc = fdot2(z.w, wv.w, acc);
  }
  feats[(size_t)row * 32 + k] = acc;
}

// ---------------------------------------------------------------------------
// CRF numerator (unchanged)
// ---------------------------------------------------------------------------
__global__ __launch_bounds__(64) void crf_num_kernel(
    const int* __restrict__ tags, const float* __restrict__ feats,
    const float* __restrict__ trans, float* __restrict__ num)
{
  int b = blockIdx.x, l = threadIdx.x;
  const int* tb = tags + b * SEQ;
  float acc = 0.f;
  for (int s = l; s < SEQ; s += 64) {
    int tg = tb[s];
    int pv = (s == 0) ? START_TAG : tb[s - 1];
    acc += trans[pv * NTAG + tg] + feats[((size_t)b * SEQ + s) * NTAG + tg];
  }
#pragma unroll
  for (int msk = 1; msk < 64; msk <<= 1) acc += __shfl_xor(acc, msk);
  if (l == 0) num[b] = acc + trans[tb[SEQ - 1] * NTAG + END_TAG];
}

// ---------------------------------------------------------------------------
// CRF stage A (unchanged from R8)
// ---------------------------------------------------------------------------
__global__ __launch_bounds__(64) void crf_seg_kernel(
    const float* __restrict__ feats, const float* __restrict__ trans,
    uint* __restrict__ segP, float* __restrict__ segL)
{
  const float L2E = 1.4426950408889634f;
  int blk = blockIdx.x;
  int b = blk >> 5, j = blk & 31;
  int tstart = 1 + 16 * j;
  int nsteps = (j == 31) ? 15 : 16;
  int lane = threadIdx.x;
  int c = lane & 15, q = lane >> 4;

  half8_t afr[2];
#pragma unroll
  for (int rt = 0; rt < 2; ++rt) {
    const float* trow = trans + (rt * 16 + c) * 32 + q * 8;
    float e[8];
#pragma unroll
    for (int i = 0; i < 8; ++i) e[i] = fexp2(trow[i] * L2E);
    uint4 u;
    u.x = packh2(e[0], e[1]); u.y = packh2(e[2], e[3]);
    u.z = packh2(e[4], e[5]); u.w = packh2(e[6], e[7]);
    afr[rt] = __builtin_bit_cast(half8_t, u);
  }
  half8_t bfr[2];
#pragma unroll
  for (int ct = 0; ct < 2; ++ct) {
    uint4 u;
    uint vals[8];
#pragma unroll
    for (int i = 0; i < 8; ++i)
      vals[i] = ((q * 8 + i) == (ct * 16 + c)) ? 0x3C00u : 0u;
    u.x = vals[0] | (vals[1] << 16);
    u.y = vals[2] | (vals[3] << 16);
    u.z = vals[4] | (vals[5] << 16);
    u.w = vals[6] | (vals[7] << 16);
    bfr[ct] = __builtin_bit_cast(half8_t, u);
  }

  __shared__ __fp16 P16[32 * 36];

  const float* fb = feats + ((size_t)b * SEQ + tstart) * NTAG;
  float Lacc = 0.f;
  float4 pre0 = *(const float4*)(fb + q * 4);
  float4 pre1 = *(const float4*)(fb + 16 + q * 4);

  for (int s = 0; s < nsteps; ++s) {
    float4 f0 = pre0, f1 = pre1;
    if (s + 1 < nsteps) {
      pre0 = *(const float4*)(fb + (s + 1) * 32 + q * 4);
      pre1 = *(const float4*)(fb + (s + 1) * 32 + 16 + q * 4);
    }
    floatx4 z4 = (floatx4){0.f, 0.f, 0.f, 0.f};
    floatx4 c00 = __builtin_amdgcn_mfma_f32_16x16x32_f16(afr[0], bfr[0], z4, 0, 0, 0);
    floatx4 c01 = __builtin_amdgcn_mfma_f32_16x16x32_f16(afr[0], bfr[1], z4, 0, 0, 0);
    floatx4 c10 = __builtin_amdgcn_mfma_f32_16x16x32_f16(afr[1], bfr[0], z4, 0, 0, 0);
    floatx4 c11 = __builtin_amdgcn_mfma_f32_16x16x32_f16(afr[1], bfr[1], z4, 0, 0, 0);
    float pf0[4], pf1[4];
    pf0[0] = fexp2(f0.x * L2E); pf0[1] = fexp2(f0.y * L2E);
    pf0[2] = fexp2(f0.z * L2E); pf0[3] = fexp2(f0.w * L2E);
    pf1[0] = fexp2(f1.x * L2E); pf1[1] = fexp2(f1.y * L2E);
    pf1[2] = fexp2(f1.z * L2E); pf1[3] = fexp2(f1.w * L2E);
    float v00[4], v01[4], v10[4], v11[4];
#pragma unroll
    for (int rg = 0; rg < 4; ++rg) {
      v00[rg] = c00[rg] * pf0[rg];
      v01[rg] = c01[rg] * pf0[rg];
      v10[rg] = c10[rg] * pf1[rg];
      v11[rg] = c11[rg] * pf1[rg];
    }
    float mx = 0.f;
#pragma unroll
    for (int rg = 0; rg < 4; ++rg)
      mx = fmaxf(mx, fmaxf(fmaxf(v00[rg], v01[rg]), fmaxf(v10[rg], v11[rg])));
    uint ub = (uint)__builtin_amdgcn_readfirstlane((int)__builtin_bit_cast(uint, mx));
    int e = (int)((ub >> 23) & 255u);
    Lacc += (float)(e - 127);
    float sc = __builtin_bit_cast(float, (uint)((254 - e) << 23));

    __syncthreads();
    {
      uint2 wv2;
      wv2.x = packh2(v00[0] * sc, v00[1] * sc);
      wv2.y = packh2(v00[2] * sc, v00[3] * sc);
      *(uint2*)(&P16[c * 36 + q * 4]) = wv2;
      wv2.x = packh2(v10[0] * sc, v10[1] * sc);
      wv2.y = packh2(v10[2] * sc, v10[3] * sc);
      *(uint2*)(&P16[c * 36 + 16 + q * 4]) = wv2;
      wv2.x = packh2(v01[0] * sc, v01[1] * sc);
      wv2.y = packh2(v01[2] * sc, v01[3] * sc);
      *(uint2*)(&P16[(16 + c) * 36 + q * 4]) = wv2;
      wv2.x = packh2(v11[0] * sc, v11[1] * sc);
      wv2.y = packh2(v11[2] * sc, v11[3] * sc);
      *(uint2*)(&P16[(16 + c) * 36 + 16 + q * 4]) = wv2;
    }
    __syncthreads();
    {
      uint2 lo0 = *(const uint2*)(&P16[c * 36 + q * 8]);
      uint2 hi0 = *(const uint2*)(&P16[c * 36 + q * 8 + 4]);
      uint4 u0; u0.x = lo0.x; u0.y = lo0.y; u0.z = hi0.x; u0.w = hi0.y;
      bfr[0] = __builtin_bit_cast(half8_t, u0);
      uint2 lo1 = *(const uint2*)(&P16[(16 + c) * 36 + q * 8]);
      uint2 hi1 = *(const uint2*)(&P16[(16 + c) * 36 + q * 8 + 4]);
      uint4 u1; u1.x = lo1.x; u1.y = lo1.y; u1.z = hi1.x; u1.w = hi1.y;
      bfr[1] = __builtin_bit_cast(half8_t, u1);
    }
  }
  __syncthreads();
  uint* gp = segP + (size_t)blk * 512;
  if (lane < 32) {
    int i = lane;
#pragma unroll
    for (int tp = 0; tp < 16; ++tp) {
      uint lo = (uint)__builtin_bit_cast(unsigned short, P16[(2 * tp) * 36 + i]);
      uint hi = (uint)__builtin_bit_cast(unsigned short, P16[(2 * tp + 1) * 36 + i]);
      gp[i * 16 + tp] = lo | (hi << 16);
    }
  }
  if (lane == 0) segL[blk] = Lacc;
}

// ---------------------------------------------------------------------------
// CRF stage B (unchanged from R8)
// ---------------------------------------------------------------------------
__global__ __launch_bounds__(64) void crf_comb_kernel(
    const float* __restrict__ feats, const float* __restrict__ trans,
    const uint* __restrict__ segP, const float* __restrict__ segL,
    float* __restrict__ den)
{
  const float L2E = 1.4426950408889634f, LN2 = 0.6931471805599453f;
  int b = blockIdx.x, l = threadIdx.x;
  int i = l & 31, hp = l >> 5;
  const float* fb = feats + (size_t)b * SEQ * NTAG;

  float sT = 0.f;
  for (int p = 0; p < 32; ++p) sT += fexp2(trans[i * 32 + p] * L2E);
  float v = (1.f + sT) * fexp2(fb[i] * L2E);
  float L = -10000.f * L2E;

  float vo = __shfl_xor(v, 1);
  uint pv = (i & 1) ? packh2(vo, v) : packh2(v, vo);

  const uint* gp0 = segP + (size_t)b * 32 * 512 + i * 16 + hp * 8;
  uint4 ra = *(const uint4*)(gp0);
  uint4 rb = *(const uint4*)(gp0 + 4);

  for (int seg = 0; seg < 32; ++seg) {
    uint4 ca = ra, cb = rb;
    if (seg + 1 < 32) {
      ra = *(const uint4*)(gp0 + (seg + 1) * 512);
      rb = *(const uint4*)(gp0 + (seg + 1) * 512 + 4);
    }
    float g0 = __shfl(__builtin_bit_cast(float, pv), hp * 16 + 0);
    float g1 = __shfl(__builtin_bit_cast(float, pv), hp * 16 + 2);
    float g2 = __shfl(__builtin_bit_cast(float, pv), hp * 16 + 4);
    float g3 = __shfl(__builtin_bit_cast(float, pv), hp * 16 + 6);
    float g4 = __shfl(__builtin_bit_cast(float, pv), hp * 16 + 8);
    float g5 = __shfl(__builtin_bit_cast(float, pv), hp * 16 + 10);
    float g6 = __shfl(__builtin_bit_cast(float, pv), hp * 16 + 12);
    float g7 = __shfl(__builtin_bit_cast(float, pv), hp * 16 + 14);
    float acc = 0.f;
    acc = fdot2(__builtin_bit_cast(uint, g0), ca.x, acc);
    acc = fdot2(__builtin_bit_cast(uint, g1), ca.y, acc);
    acc = fdot2(__builtin_bit_cast(uint, g2), ca.z, acc);
    acc = fdot2(__builtin_bit_cast(uint, g3), ca.w, acc);
    acc = fdot2(__builtin_bit_cast(uint, g4), cb.x, acc);
    acc = fdot2(__builtin_bit_cast(uint, g5), cb.y, acc);
    acc = fdot2(__builtin_bit_cast(uint, g6), cb.z, acc);
    acc = fdot2(__builtin_bit_cast(uint, g7), cb.w, acc);
    float sm = acc + __shfl_xor(acc, 32);
    uint ub = (uint)__builtin_amdgcn_readfirstlane((int)__builtin_bit_cast(uint, sm));
    int e = (int)((ub >> 23) & 255u);
    L += (float)(e - 127) + segL[b * 32 + seg];
    float sc = __builtin_bit_cast(float, (uint)((254 - e) << 23));
    v = sm * sc;
    float vo2 = __shfl_xor(v, 1);
    pv = (i & 1) ? packh2(vo2, v) : packh2(v, vo2);
  }
  float wv = v * fexp2(trans[i * 32 + END_TAG] * L2E);
#pragma unroll
  for (int msk = 1; msk <= 16; msk <<= 1) wv += __shfl_xor(wv, msk);
  if (l == 0) den[b] = (L + flog2(wv)) * LN2;
}

__global__ __launch_bounds__(128) void final_kernel(
    const float* __restrict__ num, const float* __restrict__ den,
    float* __restrict__ out)
{
  int tid = threadIdx.x;
  float v = num[tid] - den[tid];
#pragma unroll
  for (int msk = 1; msk < 64; msk <<= 1) v += __shfl_xor(v, msk);
  __shared__ float tmp[2];
  if ((tid & 63) == 0) tmp[tid >> 6] = v;
  __syncthreads();
  if (tid == 0) out[0] = (tmp[0] + tmp[1]) * (1.f / 128.f);
}

// ---------------------------------------------------------------------------
// Workspace layout (bytes): same as R8 (~51.4 MB named; gatex tail overlaps
// the later-phase buffers deliberately — gatex is dead after the chunk loop)
// ---------------------------------------------------------------------------
extern "C" void kernel_launch(void* const* d_in, const int* in_sizes, int n_in,
                              void* d_out, int out_size, void* d_ws, size_t ws_size,
                              hipStream_t stream)
{
  const int* sentence = (const int*)d_in[0];
  const int* tags = (const int*)d_in[1];
  const float* embed = (const float*)d_in[2];
  const float* Wihf = (const float*)d_in[3];
  const float* Whhf = (const float*)d_in[4];
  const float* bihf = (const float*)d_in[5];
  const float* bhhf = (const float*)d_in[6];
  const float* Wihb = (const float*)d_in[7];
  const float* Whhb = (const float*)d_in[8];
  const float* bihb = (const float*)d_in[9];
  const float* bhhb = (const float*)d_in[10];
  const float* Wout = (const float*)d_in[11];
  const float* bout = (const float*)d_in[12];
  const float* trans = (const float*)d_in[13];
  const float* h0 = (const float*)d_in[14];
  const float* c0 = (const float*)d_in[15];
  float* out = (float*)d_out;

  char* ws = (char*)d_ws;
  uint* wihI = (uint*)(ws + 0);
  uint* whh = (uint*)(ws + 262144);
  uint* woutp = (uint*)(ws + 524288);
  float* biasI = (float*)(ws + 540672);
  float* numb = (float*)(ws + 544768);
  float* denb = (float*)(ws + 545280);
  float* statec = (float*)(ws + 545792);
  uint* hh = (uint*)(ws + 1048576);
  uint* gatex = (uint*)(ws + 34603008);
  float* feats = (float*)(ws + 34603008);
  uint* segP = (uint*)(ws + 42991616);
  float* segL = (float*)(ws + 51380224);

  hipLaunchKernelGGL(prep_kernel, dim3(532), dim3(256), 0, stream,
                     Wihf, Whhf, bihf, bhhf, Wihb, Whhb, bihb, bhhb, Wout,
                     wihI, whh, woutp, biasI);
  for (int c = 0; c < 4; ++c) {
    hipLaunchKernelGGL(gemmx_kernel, dim3(1024), dim3(256), 0, stream,
                       sentence, embed, wihI, biasI, gatex, c);
    hipLaunchKernelGGL(lstm_kernel, dim3(256), dim3(512), 0, stream,
                       gatex, whh, h0, c0, statec, hh, c);
  }
  hipLaunchKernelGGL(outproj_kernel, dim3(8192), dim3(256), 0, stream,
                     hh, woutp, bout, feats);
  hipLaunchKernelGGL(crf_num_kernel, dim3(128), dim3(64), 0, stream,
                     tags, feats, trans, numb);
  hipLaunchKernelGGL(crf_seg_kernel, dim3(4096), dim3(64), 0, stream,
                     feats, trans, segP, segL);
  hipLaunchKernelGGL(crf_comb_kernel, dim3(128), dim3(64), 0, stream,
                     feats, trans, segP, segL, denb);
  hipLaunchKernelGGL(final_kernel, dim3(1), dim3(128), 0, stream,
                     numb, denb, out);
}